// Round 9
// baseline (263.912 us; speedup 1.0000x reference)
//
#include <hip/hip_runtime.h>
#include <hip/hip_bf16.h>
#include <math.h>

#define THREADS 256

typedef __bf16 bf16_t;
typedef __bf16 bf16x8 __attribute__((ext_vector_type(8)));
typedef float f32x4 __attribute__((ext_vector_type(4)));

__device__ __forceinline__ float sigmoidf_(float x) { return 1.f / (1.f + expf(-x)); }

__device__ __forceinline__ void gload_lds16(const void* g, void* l) {
    __builtin_amdgcn_global_load_lds((const __attribute__((address_space(1))) void*)g,
                                     (__attribute__((address_space(3))) void*)l, 16, 0, 0);
}

__device__ __forceinline__ bf16x8 cvt8(float4 a, float4 b) {
    bf16x8 v;
    v[0] = (bf16_t)a.x; v[1] = (bf16_t)a.y; v[2] = (bf16_t)a.z; v[3] = (bf16_t)a.w;
    v[4] = (bf16_t)b.x; v[5] = (bf16_t)b.y; v[6] = (bf16_t)b.z; v[7] = (bf16_t)b.w;
    return v;
}

// ------------------------------------------------------------------
// prep: pack transposed bf16 weights for key/val/q GEMMs.
// WbfT [256][288], WqT [128][384], bpn[256], bpq[128]
// ------------------------------------------------------------------
__global__ void prep_kernel(const float* __restrict__ W_key, const float* __restrict__ W_val,
                            const float* __restrict__ W_q, const float* __restrict__ b_key,
                            const float* __restrict__ b_val, const float* __restrict__ b_q,
                            bf16_t* __restrict__ WbfT, bf16_t* __restrict__ WqT,
                            float* __restrict__ bpn, float* __restrict__ bpq)
{
    int i = blockIdx.x * THREADS + threadIdx.x;
    const int NW = 256 * 288, NQ = 128 * 384;
    if (i < NW) {
        int c = i / 288, k = i - c * 288;
        float v = 0.f;
        if (k < 283) {
            if (c < 100) v = W_key[k * 100 + c];
            else if (c >= 128 && c < 256) v = W_val[k * 128 + (c - 128)];
        }
        WbfT[i] = (bf16_t)v;
    } else if (i < NW + NQ) {
        int j = i - NW;
        int c = j / 384, k = j - c * 384;
        WqT[j] = (bf16_t)((c < 100) ? W_q[k * 100 + c] : 0.f);
    } else if (i < NW + NQ + 256) {
        int c = i - NW - NQ;
        bpn[c] = (c < 100) ? b_key[c] : ((c >= 128 && c < 256) ? b_val[c - 128] : 0.f);
    } else if (i < NW + NQ + 256 + 128) {
        int c = i - NW - NQ - 256;
        bpq[c] = (c < 100) ? b_q[c] : 0.f;
    }
}

// ------------------------------------------------------------------
// prep2: pack GRU block-diag BTg [768][256], W1Tp [128][128],
// W2Tp [128][128], bgru[768], b1p[128]; PLUS zero cnt[2P] and AG pad rows.
// ------------------------------------------------------------------
__global__ void prep2_kernel(const float* __restrict__ W_ih, const float* __restrict__ W_hh,
                             const float* __restrict__ b_ih, const float* __restrict__ b_hh,
                             const float* __restrict__ W1, const float* __restrict__ b1,
                             const float* __restrict__ W2,
                             bf16_t* __restrict__ BTg, bf16_t* __restrict__ W1Tp,
                             bf16_t* __restrict__ W2Tp, float* __restrict__ bgru,
                             float* __restrict__ b1p,
                             int* __restrict__ cnt, int twoP,
                             bf16_t* __restrict__ AG, int padStart, int padElems)
{
    int i = blockIdx.x * THREADS + threadIdx.x;
    const int NG = 768 * 256, N1 = 128 * 128, N2 = 128 * 128;
    const int NB = NG + N1 + N2 + 768 + 128;
    if (i < NG) {
        int c = i >> 8, k = i & 255;
        float v = 0.f;
        if (c < 384) { if (k < 128) v = W_ih[k * 384 + c]; }
        else         { if (k >= 128) v = W_hh[(k - 128) * 384 + (c - 384)]; }
        BTg[i] = (bf16_t)v;
    } else if (i < NG + N1) {
        int j = i - NG; int c = j >> 7, k = j & 127;
        W1Tp[j] = (bf16_t)((c < 64) ? W1[k * 64 + c] : 0.f);
    } else if (i < NG + N1 + N2) {
        int j = i - NG - N1; int c = j >> 7, k = j & 127;
        W2Tp[j] = (bf16_t)((k < 64) ? W2[k * 128 + c] : 0.f);
    } else if (i < NG + N1 + N2 + 768) {
        int c = i - NG - N1 - N2;
        bgru[c] = (c < 384) ? b_ih[c] : b_hh[c - 384];
    } else if (i < NB) {
        int c = i - NG - N1 - N2 - 768;
        b1p[c] = (c < 64) ? b1[c] : 0.f;
    } else if (i < NB + twoP) {
        cnt[i - NB] = 0;
    } else if (i < NB + twoP + padElems) {
        int j = i - NB - twoP;
        AG[(size_t)padStart * 256 + j] = (bf16_t)0.f;
    }
}

// skip features -> skipb bf16 [Mpad,32] (27 real + 5 zero; pad rows zero)
__global__ void skip_kernel(const float* __restrict__ energy, const float* __restrict__ eta,
                            const float* __restrict__ phi, const float* __restrict__ layer,
                            const float* __restrict__ eta_l, const float* __restrict__ phi_l,
                            const float* __restrict__ ene_l, const float* __restrict__ track,
                            bf16_t* __restrict__ skipb, int N_, int Mpad)
{
    int n = blockIdx.x * THREADS + threadIdx.x;
    if (n >= Mpad) return;
    float o[32];
#pragma unroll
    for (int j = 0; j < 32; ++j) o[j] = 0.f;
    if (n < N_) {
        o[0] = (logf(energy[n]) - 4.0f) * 0.5f;
        o[1] = eta[n] * (1.f / 1.5f);
        o[2] = phi[n];
        o[3] = layer[n];
#pragma unroll
        for (int j = 0; j < 6; ++j) o[4 + j]  = eta_l[n * 6 + j] * (1.f / 1.5f);
#pragma unroll
        for (int j = 0; j < 6; ++j) o[10 + j] = phi_l[n * 6 + j];
#pragma unroll
        for (int j = 0; j < 6; ++j) o[16 + j] = ene_l[n * 6 + j];
#pragma unroll
        for (int j = 0; j < 5; ++j) o[22 + j] = track[n * 5 + j];
    }
    bf16_t* dst = skipb + (size_t)n * 32;
#pragma unroll
    for (int g = 0; g < 4; ++g) {
        bf16x8 v;
#pragma unroll
        for (int j = 0; j < 8; ++j) v[j] = (bf16_t)o[g * 8 + j];
        *(bf16x8*)(dst + g * 8) = v;
    }
}

// ------------------------------------------------------------------
// kv_gemm: DIRECT-TO-REGISTER GEMM for KVb (no LDS, no barriers).
// Block = 32 rows x 256 cols; 4 waves each own a 64-col slice and read
// the SAME 32 A-rows (wave0 HBM-miss, others L1/L2-hit -> single A pass).
// B (WbfT, 144KB) is L2-resident; frags loaded per K-step to registers.
// A-frag: lane(la,hi) row=i*16+la, k=kt+hi*8 (fp32->cvt8, or skipb bf16).
// ------------------------------------------------------------------
__global__ __launch_bounds__(256) void kv_gemm(
    const float* __restrict__ nh, const bf16_t* __restrict__ skipb,
    const bf16_t* __restrict__ BT, const float* __restrict__ bias,
    bf16_t* __restrict__ KVb, int N_)
{
    int tid = threadIdx.x;
    int w = tid >> 6, lane = tid & 63;
    int la = lane & 15, hi = lane >> 4;
    int row0 = blockIdx.x * 32;
    int col0 = w * 64;
    int r0 = row0 + la, r1 = row0 + 16 + la;
    bool ok0 = r0 < N_, ok1 = r1 < N_;
    const float* pa0 = nh + (size_t)r0 * 256 + hi * 8;
    const float* pa1 = nh + (size_t)r1 * 256 + hi * 8;

    f32x4 zero4 = {0.f, 0.f, 0.f, 0.f};
    f32x4 acc[2][4];
#pragma unroll
    for (int i = 0; i < 2; ++i)
#pragma unroll
        for (int j = 0; j < 4; ++j) acc[i][j] = zero4;

    for (int kt = 0; kt < 288; kt += 32) {
        bf16x8 a0, a1;
        if (kt < 256) {  // kt uniform across wave -> no divergence
            bf16x8 z = {};
            a0 = ok0 ? cvt8(*(const float4*)(pa0 + kt), *(const float4*)(pa0 + kt + 4)) : z;
            a1 = ok1 ? cvt8(*(const float4*)(pa1 + kt), *(const float4*)(pa1 + kt + 4)) : z;
        } else {         // skip tail: bf16, pad rows pre-zeroed
            a0 = *(const bf16x8*)(skipb + (size_t)r0 * 32 + hi * 8);
            a1 = *(const bf16x8*)(skipb + (size_t)r1 * 32 + hi * 8);
        }
        bf16x8 b[4];
#pragma unroll
        for (int j = 0; j < 4; ++j)
            b[j] = *(const bf16x8*)(BT + (size_t)(col0 + j * 16 + la) * 288 + kt + hi * 8);
#pragma unroll
        for (int j = 0; j < 4; ++j) {
            acc[0][j] = __builtin_amdgcn_mfma_f32_16x16x32_bf16(a0, b[j], acc[0][j], 0, 0, 0);
            acc[1][j] = __builtin_amdgcn_mfma_f32_16x16x32_bf16(a1, b[j], acc[1][j], 0, 0, 0);
        }
    }

#pragma unroll
    for (int j = 0; j < 4; ++j) {
        int col = col0 + j * 16 + la;
        float bb = bias[col];
#pragma unroll
        for (int i = 0; i < 2; ++i) {
#pragma unroll
            for (int r = 0; r < 4; ++r) {
                int row = row0 + i * 16 + hi * 4 + r;
                KVb[(size_t)row * 256 + col] = (bf16_t)(acc[i][j][r] + bb);
            }
        }
    }
}

// ------------------------------------------------------------------
// bf16 MFMA GEMM (modes 1-4, small GEMMs): 64x128 tile, BK=32, 4 waves,
// single-buffered LDS, 2-barrier loop. (r8 structure)
// MODE 1: A = ph fp32 [.,128] | grep fp32 [.,256]; K=384; out Qb bf16
// MODE 2: A bf16 stride K; fp32 out ldc=768   MODE 3: bf16 out + relu
// MODE 4: fp32 out = acc+bias+resid, row<Mlimit
// ------------------------------------------------------------------
template <int MODE>
__global__ __launch_bounds__(256) void mfma_gemm(
    const void* __restrict__ A0, const void* __restrict__ A1,
    const bf16_t* __restrict__ BT, const float* __restrict__ bias,
    void* __restrict__ out0v, const float* __restrict__ resid,
    int K, int Mlimit, int Nrows)
{
    __shared__ short AsS[64 * 32];   // [row][k] bf16, 64B rows
    __shared__ short BsS[128 * 32];  // [col][k]
    int tid = threadIdx.x;
    int lane = tid & 63, w = tid >> 6;
    int la = lane & 15, hi = lane >> 4;
    int m0 = (w & 1) * 32, n0 = (w >> 1) * 64;
    int row0 = blockIdx.y * 64, col0 = blockIdx.x * 128;

    f32x4 zero4 = {0.f, 0.f, 0.f, 0.f};
    f32x4 acc[2][4];
#pragma unroll
    for (int i = 0; i < 2; ++i)
#pragma unroll
        for (int j = 0; j < 4; ++j) acc[i][j] = zero4;

    const int ra = tid >> 2, ka = (tid & 3) * 8;   // A: 1 chunk (16B) / thread
    const int c1 = tid + 256;                       // B: 2 chunks / thread
    const int rb0 = tid >> 2, kb0 = (tid & 3) * 8;
    const int rb1 = c1 >> 2,  kb1 = (c1 & 3) * 8;

    for (int kt = 0; kt < K; kt += 32) {
        int gmA = row0 + ra;
        if (MODE == 1) {
            int gk = kt + ka;
            bf16x8 v = {};
            if (gmA < Nrows) {
                const float* s = (gk < 128) ? ((const float*)A0 + (size_t)gmA * 128 + gk)
                                            : ((const float*)A1 + (size_t)gmA * 256 + (gk - 128));
                v = cvt8(*(const float4*)s, *(const float4*)(s + 4));
            }
            *(bf16x8*)(AsS + (size_t)tid * 8) = v;
        } else {
            gload_lds16((const bf16_t*)A0 + (size_t)gmA * K + kt + ka,
                        AsS + (size_t)tid * 8);
        }
        gload_lds16(BT + (size_t)(col0 + rb0) * K + kt + kb0, BsS + (size_t)tid * 8);
        gload_lds16(BT + (size_t)(col0 + rb1) * K + kt + kb1, BsS + (size_t)c1 * 8);
        __syncthreads();
        bf16x8 a[2], b[4];
#pragma unroll
        for (int i = 0; i < 2; ++i)
            a[i] = *(const bf16x8*)(AsS + (m0 + i * 16 + la) * 32 + hi * 8);
#pragma unroll
        for (int j = 0; j < 4; ++j)
            b[j] = *(const bf16x8*)(BsS + (n0 + j * 16 + la) * 32 + hi * 8);
#pragma unroll
        for (int i = 0; i < 2; ++i)
#pragma unroll
            for (int j = 0; j < 4; ++j)
                acc[i][j] = __builtin_amdgcn_mfma_f32_16x16x32_bf16(a[i], b[j], acc[i][j], 0, 0, 0);
        __syncthreads();
    }

#pragma unroll
    for (int i = 0; i < 2; ++i) {
#pragma unroll
        for (int j = 0; j < 4; ++j) {
            int col = col0 + n0 + j * 16 + la;
            float bb = bias[col];
#pragma unroll
            for (int r = 0; r < 4; ++r) {
                int row = row0 + m0 + i * 16 + hi * 4 + r;
                float v = acc[i][j][r] + bb;
                if (MODE == 1) {
                    ((bf16_t*)out0v)[(size_t)row * 128 + col] = (bf16_t)v;
                } else if (MODE == 2) {
                    ((float*)out0v)[(size_t)row * 768 + col] = v;
                } else if (MODE == 3) {
                    ((bf16_t*)out0v)[(size_t)row * 128 + col] = (bf16_t)fmaxf(v, 0.f);
                } else {  // MODE 4
                    if (row < Mlimit)
                        ((float*)out0v)[(size_t)row * 128 + col] = v + resid[(size_t)row * 128 + col];
                }
            }
        }
    }
}

// ------------------------------------------------------------------
// CSR build (cnt zeroed by prep2)
// ------------------------------------------------------------------
__global__ void hist_kernel(const int* __restrict__ dst, int* __restrict__ cnt, int E_)
{
    int i = blockIdx.x * THREADS + threadIdx.x;
    if (i < E_) atomicAdd(&cnt[dst[i]], 1);
}

// single-block shfl-based exclusive scan; 1024 threads x 10 elems covers P+1<=10240
__global__ void scan_kernel(const int* __restrict__ cnt, int* __restrict__ offb, int P_)
{
    __shared__ int wsum[16];
    int tid = threadIdx.x;
    int lane = tid & 63, w = tid >> 6;
    int base = tid * 10;
    int c[10];
    int s = 0;
#pragma unroll
    for (int j = 0; j < 10; ++j) {
        int i = base + j;
        c[j] = (i < P_) ? cnt[i] : 0;
        s += c[j];
    }
    int pre = s;
    for (int o = 1; o < 64; o <<= 1) {
        int t = __shfl_up(pre, o);
        if (lane >= o) pre += t;
    }
    if (lane == 63) wsum[w] = pre;
    __syncthreads();
    if (w == 0 && lane < 16) {
        int v = wsum[lane];
        for (int o = 1; o < 16; o <<= 1) {
            int t = __shfl_up(v, o, 16);
            if (lane >= o) v += t;
        }
        wsum[lane] = v;
    }
    __syncthreads();
    int waveoff = (w == 0) ? 0 : wsum[w - 1];
    int run = waveoff + pre - s;
#pragma unroll
    for (int j = 0; j < 10; ++j) {
        int i = base + j;
        if (i <= P_) offb[i] = run;
        run += c[j];
    }
}

// fill: store SRC NODE ID directly
__global__ void fill_src_kernel(const int* __restrict__ dst, const int* __restrict__ src,
                                const int* __restrict__ offb, int* __restrict__ cur,
                                int* __restrict__ csrc, int E_)
{
    int i = blockIdx.x * THREADS + threadIdx.x;
    if (i < E_) {
        int d = dst[i];
        int pos = atomicAdd(&cur[d], 1);
        csrc[offb[d] + pos] = src[i];
    }
}

// ------------------------------------------------------------------
// fused attention + gather + rms/sigmoid gate: 1 wave/particle, 4/block.
// lane = (g=lane>>4 edge-group, c=lane&15 col-chunk). KVb row: K 0..127,
// V 128..255. After cross-group reduce, all lanes hold the row sums ->
// gate computed in-register, AG = [gated | h] bf16 written directly.
// ------------------------------------------------------------------
__global__ __launch_bounds__(256) void edge_kernel(
    const int* __restrict__ offb, const int* __restrict__ csrc,
    const bf16_t* __restrict__ KVb, const bf16_t* __restrict__ Qb,
    const float* __restrict__ ph, const float* __restrict__ rms_w,
    const float* __restrict__ lin_w, bf16_t* __restrict__ AG, int P_)
{
    int tid = threadIdx.x;
    int p = blockIdx.x * 4 + (tid >> 6);
    if (p >= P_) return;
    int lane = tid & 63;
    int c = lane & 15, g = lane >> 4;

    bf16x8 q8 = *(const bf16x8*)(Qb + (size_t)p * 128 + c * 8);
    float qf[8];
#pragma unroll
    for (int j = 0; j < 8; ++j) qf[j] = (float)q8[j];

    int s0 = offb[p], e0 = offb[p + 1];
    float acc[8] = {};

    int i = s0 + g;
    for (; i + 12 < e0; i += 16) {
        int n0 = csrc[i], n1 = csrc[i + 4], n2 = csrc[i + 8], n3 = csrc[i + 12];
        const bf16_t* b0 = KVb + (size_t)n0 * 256 + c * 8;
        const bf16_t* b1 = KVb + (size_t)n1 * 256 + c * 8;
        const bf16_t* b2 = KVb + (size_t)n2 * 256 + c * 8;
        const bf16_t* b3 = KVb + (size_t)n3 * 256 + c * 8;
        bf16x8 k0 = *(const bf16x8*)b0, v0 = *(const bf16x8*)(b0 + 128);
        bf16x8 k1 = *(const bf16x8*)b1, v1 = *(const bf16x8*)(b1 + 128);
        bf16x8 k2 = *(const bf16x8*)b2, v2 = *(const bf16x8*)(b2 + 128);
        bf16x8 k3 = *(const bf16x8*)b3, v3 = *(const bf16x8*)(b3 + 128);
        float d0 = 0.f, d1 = 0.f, d2 = 0.f, d3 = 0.f;
#pragma unroll
        for (int j = 0; j < 8; ++j) {
            d0 += qf[j] * (float)k0[j]; d1 += qf[j] * (float)k1[j];
            d2 += qf[j] * (float)k2[j]; d3 += qf[j] * (float)k3[j];
        }
        d0 += __shfl_xor(d0, 1); d1 += __shfl_xor(d1, 1); d2 += __shfl_xor(d2, 1); d3 += __shfl_xor(d3, 1);
        d0 += __shfl_xor(d0, 2); d1 += __shfl_xor(d1, 2); d2 += __shfl_xor(d2, 2); d3 += __shfl_xor(d3, 2);
        d0 += __shfl_xor(d0, 4); d1 += __shfl_xor(d1, 4); d2 += __shfl_xor(d2, 4); d3 += __shfl_xor(d3, 4);
        d0 += __shfl_xor(d0, 8); d1 += __shfl_xor(d1, 8); d2 += __shfl_xor(d2, 8); d3 += __shfl_xor(d3, 8);
        float a0 = fmaxf(d0 * 0.1f, 0.f), a1 = fmaxf(d1 * 0.1f, 0.f);
        float a2 = fmaxf(d2 * 0.1f, 0.f), a3 = fmaxf(d3 * 0.1f, 0.f);
#pragma unroll
        for (int j = 0; j < 8; ++j)
            acc[j] += a0 * (float)v0[j] + a1 * (float)v1[j]
                    + a2 * (float)v2[j] + a3 * (float)v3[j];
    }
    for (; i < e0; i += 4) {
        int nA = csrc[i];
        const bf16_t* bA = KVb + (size_t)nA * 256 + c * 8;
        bf16x8 kA = *(const bf16x8*)bA;
        bf16x8 vA = *(const bf16x8*)(bA + 128);
        float dA = 0.f;
#pragma unroll
        for (int j = 0; j < 8; ++j) dA += qf[j] * (float)kA[j];
        dA += __shfl_xor(dA, 1);
        dA += __shfl_xor(dA, 2);
        dA += __shfl_xor(dA, 4);
        dA += __shfl_xor(dA, 8);
        float aA = fmaxf(dA * 0.1f, 0.f);
#pragma unroll
        for (int j = 0; j < 8; ++j) acc[j] += aA * (float)vA[j];
    }

    // reduce across the 4 edge-groups; afterwards every lane holds totals
#pragma unroll
    for (int j = 0; j < 8; ++j) {
        acc[j] += __shfl_xor(acc[j], 16);
        acc[j] += __shfl_xor(acc[j], 32);
    }

    // fused rms-norm * sigmoid gate (was gate_kernel)
    float ss = 0.f;
#pragma unroll
    for (int j = 0; j < 8; ++j) ss += acc[j] * acc[j];
    ss += __shfl_xor(ss, 1); ss += __shfl_xor(ss, 2); ss += __shfl_xor(ss, 4); ss += __shfl_xor(ss, 8);
    float scale = rsqrtf(ss * (1.f / 128.f) + 1e-6f);
    if (g == 0) {
        int cb = c * 8;
        const float* hp = ph + (size_t)p * 128 + cb;
        float4 ha = *(const float4*)hp, hb = *(const float4*)(hp + 4);
        float hv[8] = {ha.x, ha.y, ha.z, ha.w, hb.x, hb.y, hb.z, hb.w};
        bf16x8 gv, hvb;
#pragma unroll
        for (int j = 0; j < 8; ++j) {
            float wsv = acc[j];
            float rv = wsv * scale * rms_w[cb + j];
            gv[j] = (bf16_t)(rv * sigmoidf_(wsv * lin_w[cb + j]));
            hvb[j] = (bf16_t)hv[j];
        }
        *(bf16x8*)(AG + (size_t)p * 256 + cb) = gv;
        *(bf16x8*)(AG + (size_t)p * 256 + 128 + cb) = hvb;
    }
}

// ------------------------------------------------------------------
// gru+ln pointwise: read G768 [Mq,768] fp32 (gi|gh), h=ph fp32;
// compute h_new, LayerNorm -> LNb bf16 [Mq,128]
// ------------------------------------------------------------------
__global__ void gru_ln_kernel(const float* __restrict__ G768, const float* __restrict__ ph,
                              const float* __restrict__ ln_g, const float* __restrict__ ln_b,
                              bf16_t* __restrict__ LNb, int P_, int Mq)
{
    int tid = threadIdx.x;
    int g = tid >> 4, s = tid & 15;
    int p = blockIdx.x * 16 + g;
    if (p >= Mq) return;
    int cb = s * 8;
    if (p >= P_) {
        bf16x8 z = {};
        *(bf16x8*)(LNb + (size_t)p * 128 + cb) = z;
        return;
    }
    const float* G = G768 + (size_t)p * 768;
    float ir[8], iz[8], in_[8], hr[8], hz[8], hn_[8], hv[8];
#pragma unroll
    for (int q = 0; q < 2; ++q) {
        float4 v;
        v = *(const float4*)(G + cb + q * 4);        ir[q*4]=v.x; ir[q*4+1]=v.y; ir[q*4+2]=v.z; ir[q*4+3]=v.w;
        v = *(const float4*)(G + 128 + cb + q * 4);  iz[q*4]=v.x; iz[q*4+1]=v.y; iz[q*4+2]=v.z; iz[q*4+3]=v.w;
        v = *(const float4*)(G + 256 + cb + q * 4);  in_[q*4]=v.x; in_[q*4+1]=v.y; in_[q*4+2]=v.z; in_[q*4+3]=v.w;
        v = *(const float4*)(G + 384 + cb + q * 4);  hr[q*4]=v.x; hr[q*4+1]=v.y; hr[q*4+2]=v.z; hr[q*4+3]=v.w;
        v = *(const float4*)(G + 512 + cb + q * 4);  hz[q*4]=v.x; hz[q*4+1]=v.y; hz[q*4+2]=v.z; hz[q*4+3]=v.w;
        v = *(const float4*)(G + 640 + cb + q * 4);  hn_[q*4]=v.x; hn_[q*4+1]=v.y; hn_[q*4+2]=v.z; hn_[q*4+3]=v.w;
        v = *(const float4*)(ph + (size_t)p * 128 + cb + q * 4);
        hv[q*4]=v.x; hv[q*4+1]=v.y; hv[q*4+2]=v.z; hv[q*4+3]=v.w;
    }
    float hn[8];
    float sm = 0.f, sq = 0.f;
#pragma unroll
    for (int j = 0; j < 8; ++j) {
        float r = sigmoidf_(ir[j] + hr[j]);
        float z = sigmoidf_(iz[j] + hz[j]);
        float n = tanhf(in_[j] + r * hn_[j]);
        hn[j] = (1.f - z) * n + z * hv[j];
        sm += hn[j]; sq += hn[j] * hn[j];
    }
    sm += __shfl_xor(sm, 1); sm += __shfl_xor(sm, 2); sm += __shfl_xor(sm, 4); sm += __shfl_xor(sm, 8);
    sq += __shfl_xor(sq, 1); sq += __shfl_xor(sq, 2); sq += __shfl_xor(sq, 4); sq += __shfl_xor(sq, 8);
    float mu = sm * (1.f / 128.f);
    float var = sq * (1.f / 128.f) - mu * mu;
    float iv = rsqrtf(var + 1e-5f);
    bf16x8 o;
#pragma unroll
    for (int j = 0; j < 8; ++j) {
        int c = cb + j;
        o[j] = (bf16_t)((hn[j] - mu) * iv * ln_g[c] + ln_b[c]);
    }
    *(bf16x8*)(LNb + (size_t)p * 128 + cb) = o;
}

// ------------------------------------------------------------------
extern "C" void kernel_launch(void* const* d_in, const int* in_sizes, int n_in,
                              void* d_out, int out_size, void* d_ws, size_t ws_size,
                              hipStream_t stream)
{
    const float* nh      = (const float*)d_in[0];
    const float* energy  = (const float*)d_in[1];
    const float* eta     = (const float*)d_in[2];
    const float* phi     = (const float*)d_in[3];
    const float* layer   = (const float*)d_in[4];
    const float* eta_l   = (const float*)d_in[5];
    const float* phi_l   = (const float*)d_in[6];
    const float* ene_l   = (const float*)d_in[7];
    const float* track   = (const float*)d_in[8];
    const float* ph      = (const float*)d_in[9];
    const float* grep    = (const float*)d_in[10];
    const int*   esrc    = (const int*)d_in[11];
    const int*   edst    = (const int*)d_in[12];
    const float* W_key   = (const float*)d_in[13];
    const float* b_key   = (const float*)d_in[14];
    const float* W_val   = (const float*)d_in[15];
    const float* b_val   = (const float*)d_in[16];
    const float* W_q     = (const float*)d_in[17];
    const float* b_q     = (const float*)d_in[18];
    const float* W_ih    = (const float*)d_in[19];
    const float* b_ih    = (const float*)d_in[20];
    const float* W_hh    = (const float*)d_in[21];
    const float* b_hh    = (const float*)d_in[22];
    const float* ln_g    = (const float*)d_in[23];
    const float* ln_b    = (const float*)d_in[24];
    const float* W1      = (const float*)d_in[25];
    const float* b1      = (const float*)d_in[26];
    const float* W2      = (const float*)d_in[27];
    const float* b2      = (const float*)d_in[28];
    const float* rms_w   = (const float*)d_in[29];
    const float* lin_w   = (const float*)d_in[30];

    const int N = in_sizes[1];
    const int P = in_sizes[9] / 128;
    const int E = in_sizes[11];
    const int Mpad = ((N + 127) / 128) * 128;   // 100096
    const int Mq   = ((P + 127) / 128) * 128;   // 10112

    // workspace layout (byte offsets, 256B aligned)
    char* base = (char*)d_ws;
    size_t off = 0;
    auto alloc = [&](size_t bytes) { void* p = base + off; off = (off + bytes + 255) & ~(size_t)255; return p; };
    bf16_t* skipb = (bf16_t*)alloc((size_t)Mpad * 32 * 2);    // 6.4 MB
    bf16_t* WbfT  = (bf16_t*)alloc(256 * 288 * 2);
    bf16_t* WqT   = (bf16_t*)alloc(128 * 384 * 2);
    float*  bpn   = (float*)alloc(256 * 4);
    float*  bpq   = (float*)alloc(128 * 4);
    bf16_t* KVb   = (bf16_t*)alloc((size_t)Mpad * 256 * 2);   // 51.2 MB interleaved K|V
    bf16_t* Qb    = (bf16_t*)alloc((size_t)Mq * 128 * 2);
    // cnt and cur MUST be contiguous: prep2 zeroes cnt[0..2P)
    int*    cnt   = (int*)alloc((size_t)(2 * P) * 4);
    int*    cur   = cnt + P;
    int*    offb  = (int*)alloc((size_t)(P + 1) * 4);
    int*    csrc  = (int*)alloc((size_t)E * 4);
    // node-update buffers
    bf16_t* AG    = (bf16_t*)alloc((size_t)Mq * 256 * 2);
    bf16_t* BTg   = (bf16_t*)alloc(768 * 256 * 2);
    bf16_t* W1Tp  = (bf16_t*)alloc(128 * 128 * 2);
    bf16_t* W2Tp  = (bf16_t*)alloc(128 * 128 * 2);
    float*  bgru  = (float*)alloc(768 * 4);
    float*  b1p   = (float*)alloc(128 * 4);
    float*  G768  = (float*)alloc((size_t)Mq * 768 * 4);      // 31 MB
    bf16_t* LNb   = (bf16_t*)alloc((size_t)Mq * 128 * 2);
    bf16_t* M1    = (bf16_t*)alloc((size_t)Mq * 128 * 2);

    // 1. weight prep (+ cnt zero + AG pad zero) + skip features
    {
        int total = 256 * 288 + 128 * 384 + 256 + 128;
        prep_kernel<<<(total + THREADS - 1) / THREADS, THREADS, 0, stream>>>(
            W_key, W_val, W_q, b_key, b_val, b_q, WbfT, WqT, bpn, bpq);
        int padElems = (Mq - P) * 256;
        int total2 = 768 * 256 + 128 * 128 + 128 * 128 + 768 + 128 + 2 * P + padElems;
        prep2_kernel<<<(total2 + THREADS - 1) / THREADS, THREADS, 0, stream>>>(
            W_ih, W_hh, b_ih, b_hh, W1, b1, W2, BTg, W1Tp, W2Tp, bgru, b1p,
            cnt, 2 * P, AG, P, padElems);
        skip_kernel<<<(Mpad + THREADS - 1) / THREADS, THREADS, 0, stream>>>(
            energy, eta, phi, layer, eta_l, phi_l, ene_l, track, skipb, N, Mpad);
    }
    // 2. K/V GEMM: direct-to-register (no LDS/barriers); Q GEMM: LDS path
    kv_gemm<<<Mpad / 32, THREADS, 0, stream>>>(nh, skipb, WbfT, bpn, KVb, N);
    mfma_gemm<1><<<dim3(1, Mq / 64), THREADS, 0, stream>>>(
        ph, grep, WqT, bpq, Qb, nullptr, 384, 0, P);
    // 3. CSR build (src ids stored directly)
    hist_kernel<<<(E + THREADS - 1) / THREADS, THREADS, 0, stream>>>(edst, cnt, E);
    scan_kernel<<<1, 1024, 0, stream>>>(cnt, offb, P);
    fill_src_kernel<<<(E + THREADS - 1) / THREADS, THREADS, 0, stream>>>(
        edst, esrc, offb, cur, csrc, E);
    // 4. fused attention + gather + gate -> AG
    edge_kernel<<<(P + 3) / 4, THREADS, 0, stream>>>(
        offb, csrc, KVb, Qb, ph, rms_w, lin_w, AG, P);
    // 5. node update: GRU GEMM -> pointwise+LN -> MLP1 -> MLP2+residual
    mfma_gemm<2><<<dim3(6, Mq / 64), THREADS, 0, stream>>>(
        AG, nullptr, BTg, bgru, G768, nullptr, 256, 0, Mq);
    gru_ln_kernel<<<Mq / 16, THREADS, 0, stream>>>(G768, ph, ln_g, ln_b, LNb, P, Mq);
    mfma_gemm<3><<<dim3(1, Mq / 64), THREADS, 0, stream>>>(
        LNb, nullptr, W1Tp, b1p, M1, nullptr, 128, 0, Mq);
    mfma_gemm<4><<<dim3(1, Mq / 64), THREADS, 0, stream>>>(
        M1, nullptr, W2Tp, b2, d_out, ph, 128, P, Mq);
}

// Round 10
// 262.125 us; speedup vs baseline: 1.0068x; 1.0068x over previous
//
#include <hip/hip_runtime.h>
#include <hip/hip_bf16.h>
#include <math.h>

#define THREADS 256

typedef __bf16 bf16_t;
typedef __bf16 bf16x8 __attribute__((ext_vector_type(8)));
typedef float f32x4 __attribute__((ext_vector_type(4)));

__device__ __forceinline__ float sigmoidf_(float x) { return 1.f / (1.f + expf(-x)); }

__device__ __forceinline__ void gload_lds16(const void* g, void* l) {
    __builtin_amdgcn_global_load_lds((const __attribute__((address_space(1))) void*)g,
                                     (__attribute__((address_space(3))) void*)l, 16, 0, 0);
}

__device__ __forceinline__ bf16x8 cvt8(float4 a, float4 b) {
    bf16x8 v;
    v[0] = (bf16_t)a.x; v[1] = (bf16_t)a.y; v[2] = (bf16_t)a.z; v[3] = (bf16_t)a.w;
    v[4] = (bf16_t)b.x; v[5] = (bf16_t)b.y; v[6] = (bf16_t)b.z; v[7] = (bf16_t)b.w;
    return v;
}

// ------------------------------------------------------------------
// prep: pack transposed bf16 weights for key/val/q GEMMs.
// WbfT [256][288], WqT [128][384], bpn[256], bpq[128]
// ------------------------------------------------------------------
__global__ void prep_kernel(const float* __restrict__ W_key, const float* __restrict__ W_val,
                            const float* __restrict__ W_q, const float* __restrict__ b_key,
                            const float* __restrict__ b_val, const float* __restrict__ b_q,
                            bf16_t* __restrict__ WbfT, bf16_t* __restrict__ WqT,
                            float* __restrict__ bpn, float* __restrict__ bpq)
{
    int i = blockIdx.x * THREADS + threadIdx.x;
    const int NW = 256 * 288, NQ = 128 * 384;
    if (i < NW) {
        int c = i / 288, k = i - c * 288;
        float v = 0.f;
        if (k < 283) {
            if (c < 100) v = W_key[k * 100 + c];
            else if (c >= 128 && c < 256) v = W_val[k * 128 + (c - 128)];
        }
        WbfT[i] = (bf16_t)v;
    } else if (i < NW + NQ) {
        int j = i - NW;
        int c = j / 384, k = j - c * 384;
        WqT[j] = (bf16_t)((c < 100) ? W_q[k * 100 + c] : 0.f);
    } else if (i < NW + NQ + 256) {
        int c = i - NW - NQ;
        bpn[c] = (c < 100) ? b_key[c] : ((c >= 128 && c < 256) ? b_val[c - 128] : 0.f);
    } else if (i < NW + NQ + 256 + 128) {
        int c = i - NW - NQ - 256;
        bpq[c] = (c < 100) ? b_q[c] : 0.f;
    }
}

// ------------------------------------------------------------------
// prep2: pack GRU block-diag BTg [768][256], W1Tp [128][128],
// W2Tp [128][128], bgru[768], b1p[128]; PLUS zero cnt[2P] and AG pad rows.
// ------------------------------------------------------------------
__global__ void prep2_kernel(const float* __restrict__ W_ih, const float* __restrict__ W_hh,
                             const float* __restrict__ b_ih, const float* __restrict__ b_hh,
                             const float* __restrict__ W1, const float* __restrict__ b1,
                             const float* __restrict__ W2,
                             bf16_t* __restrict__ BTg, bf16_t* __restrict__ W1Tp,
                             bf16_t* __restrict__ W2Tp, float* __restrict__ bgru,
                             float* __restrict__ b1p,
                             int* __restrict__ cnt, int twoP,
                             bf16_t* __restrict__ AG, int padStart, int padElems)
{
    int i = blockIdx.x * THREADS + threadIdx.x;
    const int NG = 768 * 256, N1 = 128 * 128, N2 = 128 * 128;
    const int NB = NG + N1 + N2 + 768 + 128;
    if (i < NG) {
        int c = i >> 8, k = i & 255;
        float v = 0.f;
        if (c < 384) { if (k < 128) v = W_ih[k * 384 + c]; }
        else         { if (k >= 128) v = W_hh[(k - 128) * 384 + (c - 384)]; }
        BTg[i] = (bf16_t)v;
    } else if (i < NG + N1) {
        int j = i - NG; int c = j >> 7, k = j & 127;
        W1Tp[j] = (bf16_t)((c < 64) ? W1[k * 64 + c] : 0.f);
    } else if (i < NG + N1 + N2) {
        int j = i - NG - N1; int c = j >> 7, k = j & 127;
        W2Tp[j] = (bf16_t)((k < 64) ? W2[k * 128 + c] : 0.f);
    } else if (i < NG + N1 + N2 + 768) {
        int c = i - NG - N1 - N2;
        bgru[c] = (c < 384) ? b_ih[c] : b_hh[c - 384];
    } else if (i < NB) {
        int c = i - NG - N1 - N2 - 768;
        b1p[c] = (c < 64) ? b1[c] : 0.f;
    } else if (i < NB + twoP) {
        cnt[i - NB] = 0;
    } else if (i < NB + twoP + padElems) {
        int j = i - NB - twoP;
        AG[(size_t)padStart * 256 + j] = (bf16_t)0.f;
    }
}

// skip features -> skipb bf16 [Mpad,32] (27 real + 5 zero; pad rows zero)
__global__ void skip_kernel(const float* __restrict__ energy, const float* __restrict__ eta,
                            const float* __restrict__ phi, const float* __restrict__ layer,
                            const float* __restrict__ eta_l, const float* __restrict__ phi_l,
                            const float* __restrict__ ene_l, const float* __restrict__ track,
                            bf16_t* __restrict__ skipb, int N_, int Mpad)
{
    int n = blockIdx.x * THREADS + threadIdx.x;
    if (n >= Mpad) return;
    float o[32];
#pragma unroll
    for (int j = 0; j < 32; ++j) o[j] = 0.f;
    if (n < N_) {
        o[0] = (logf(energy[n]) - 4.0f) * 0.5f;
        o[1] = eta[n] * (1.f / 1.5f);
        o[2] = phi[n];
        o[3] = layer[n];
#pragma unroll
        for (int j = 0; j < 6; ++j) o[4 + j]  = eta_l[n * 6 + j] * (1.f / 1.5f);
#pragma unroll
        for (int j = 0; j < 6; ++j) o[10 + j] = phi_l[n * 6 + j];
#pragma unroll
        for (int j = 0; j < 6; ++j) o[16 + j] = ene_l[n * 6 + j];
#pragma unroll
        for (int j = 0; j < 5; ++j) o[22 + j] = track[n * 5 + j];
    }
    bf16_t* dst = skipb + (size_t)n * 32;
#pragma unroll
    for (int g = 0; g < 4; ++g) {
        bf16x8 v;
#pragma unroll
        for (int j = 0; j < 8; ++j) v[j] = (bf16_t)o[g * 8 + j];
        *(bf16x8*)(dst + g * 8) = v;
    }
}

// ------------------------------------------------------------------
// kv_gemm: direct-to-register GEMM for KVb (no LDS, no barriers),
// FULLY UNROLLED K-loop + 1-deep register double-buffer so the compiler
// issues next-step loads BEFORE current MFMAs (r9 was serialized: VGPR=56).
// Block = 32 rows x 256 cols; 4 waves each own a 64-col slice, read the
// SAME 32 A-rows (single A pass; L1/L2/L3 dedups). B (144KB) L2-resident.
// ------------------------------------------------------------------
__global__ __launch_bounds__(256) void kv_gemm(
    const float* __restrict__ nh, const bf16_t* __restrict__ skipb,
    const bf16_t* __restrict__ BT, const float* __restrict__ bias,
    bf16_t* __restrict__ KVb, int N_)
{
    int tid = threadIdx.x;
    int w = tid >> 6, lane = tid & 63;
    int la = lane & 15, hi = lane >> 4;
    int row0 = blockIdx.x * 32;
    int col0 = w * 64;
    int r0 = row0 + la, r1 = row0 + 16 + la;
    bool ok0 = r0 < N_, ok1 = r1 < N_;
    const float* pa0 = nh + (size_t)r0 * 256 + hi * 8;
    const float* pa1 = nh + (size_t)r1 * 256 + hi * 8;
    const bf16_t* pb = BT + (size_t)(col0 + la) * 288 + hi * 8;  // + j*16*288 + kt

    f32x4 zero4 = {0.f, 0.f, 0.f, 0.f};
    f32x4 acc[2][4];
#pragma unroll
    for (int i = 0; i < 2; ++i)
#pragma unroll
        for (int j = 0; j < 4; ++j) acc[i][j] = zero4;

    const int NT = 9;  // K=288, BK=32
    bf16x8 a0[2], a1[2], b[2][4];

    // static-indexed loader (kt compile-time after unroll)
    auto loadStep = [&](int t, int buf) {
        int kt = t * 32;
        if (kt < 256) {
            bf16x8 z = {};
            a0[buf] = ok0 ? cvt8(*(const float4*)(pa0 + kt), *(const float4*)(pa0 + kt + 4)) : z;
            a1[buf] = ok1 ? cvt8(*(const float4*)(pa1 + kt), *(const float4*)(pa1 + kt + 4)) : z;
        } else {  // skip tail: bf16, pad rows pre-zeroed
            a0[buf] = *(const bf16x8*)(skipb + (size_t)r0 * 32 + hi * 8);
            a1[buf] = *(const bf16x8*)(skipb + (size_t)r1 * 32 + hi * 8);
        }
#pragma unroll
        for (int j = 0; j < 4; ++j)
            b[buf][j] = *(const bf16x8*)(pb + (size_t)j * 16 * 288 + kt);
    };

    loadStep(0, 0);
#pragma unroll
    for (int t = 0; t < NT; ++t) {
        int cur = t & 1, nxt = cur ^ 1;
        if (t + 1 < NT) loadStep(t + 1, nxt);   // issue ahead of MFMAs
#pragma unroll
        for (int j = 0; j < 4; ++j) {
            acc[0][j] = __builtin_amdgcn_mfma_f32_16x16x32_bf16(a0[cur], b[cur][j], acc[0][j], 0, 0, 0);
            acc[1][j] = __builtin_amdgcn_mfma_f32_16x16x32_bf16(a1[cur], b[cur][j], acc[1][j], 0, 0, 0);
        }
    }

#pragma unroll
    for (int j = 0; j < 4; ++j) {
        int col = col0 + j * 16 + la;
        float bb = bias[col];
#pragma unroll
        for (int i = 0; i < 2; ++i) {
#pragma unroll
            for (int r = 0; r < 4; ++r) {
                int row = row0 + i * 16 + hi * 4 + r;
                KVb[(size_t)row * 256 + col] = (bf16_t)(acc[i][j][r] + bb);
            }
        }
    }
}

// ------------------------------------------------------------------
// bf16 MFMA GEMM (modes 1-4, small GEMMs): 64x128 tile, BK=32, 4 waves,
// single-buffered LDS, 2-barrier loop. (r8 structure)
// MODE 1: A = ph fp32 [.,128] | grep fp32 [.,256]; K=384; out Qb bf16
// MODE 2: A bf16 stride K; fp32 out ldc=768   MODE 3: bf16 out + relu
// MODE 4: fp32 out = acc+bias+resid, row<Mlimit
// ------------------------------------------------------------------
template <int MODE>
__global__ __launch_bounds__(256) void mfma_gemm(
    const void* __restrict__ A0, const void* __restrict__ A1,
    const bf16_t* __restrict__ BT, const float* __restrict__ bias,
    void* __restrict__ out0v, const float* __restrict__ resid,
    int K, int Mlimit, int Nrows)
{
    __shared__ short AsS[64 * 32];   // [row][k] bf16, 64B rows
    __shared__ short BsS[128 * 32];  // [col][k]
    int tid = threadIdx.x;
    int lane = tid & 63, w = tid >> 6;
    int la = lane & 15, hi = lane >> 4;
    int m0 = (w & 1) * 32, n0 = (w >> 1) * 64;
    int row0 = blockIdx.y * 64, col0 = blockIdx.x * 128;

    f32x4 zero4 = {0.f, 0.f, 0.f, 0.f};
    f32x4 acc[2][4];
#pragma unroll
    for (int i = 0; i < 2; ++i)
#pragma unroll
        for (int j = 0; j < 4; ++j) acc[i][j] = zero4;

    const int ra = tid >> 2, ka = (tid & 3) * 8;   // A: 1 chunk (16B) / thread
    const int c1 = tid + 256;                       // B: 2 chunks / thread
    const int rb0 = tid >> 2, kb0 = (tid & 3) * 8;
    const int rb1 = c1 >> 2,  kb1 = (c1 & 3) * 8;

    for (int kt = 0; kt < K; kt += 32) {
        int gmA = row0 + ra;
        if (MODE == 1) {
            int gk = kt + ka;
            bf16x8 v = {};
            if (gmA < Nrows) {
                const float* s = (gk < 128) ? ((const float*)A0 + (size_t)gmA * 128 + gk)
                                            : ((const float*)A1 + (size_t)gmA * 256 + (gk - 128));
                v = cvt8(*(const float4*)s, *(const float4*)(s + 4));
            }
            *(bf16x8*)(AsS + (size_t)tid * 8) = v;
        } else {
            gload_lds16((const bf16_t*)A0 + (size_t)gmA * K + kt + ka,
                        AsS + (size_t)tid * 8);
        }
        gload_lds16(BT + (size_t)(col0 + rb0) * K + kt + kb0, BsS + (size_t)tid * 8);
        gload_lds16(BT + (size_t)(col0 + rb1) * K + kt + kb1, BsS + (size_t)c1 * 8);
        __syncthreads();
        bf16x8 a[2], b[4];
#pragma unroll
        for (int i = 0; i < 2; ++i)
            a[i] = *(const bf16x8*)(AsS + (m0 + i * 16 + la) * 32 + hi * 8);
#pragma unroll
        for (int j = 0; j < 4; ++j)
            b[j] = *(const bf16x8*)(BsS + (n0 + j * 16 + la) * 32 + hi * 8);
#pragma unroll
        for (int i = 0; i < 2; ++i)
#pragma unroll
            for (int j = 0; j < 4; ++j)
                acc[i][j] = __builtin_amdgcn_mfma_f32_16x16x32_bf16(a[i], b[j], acc[i][j], 0, 0, 0);
        __syncthreads();
    }

#pragma unroll
    for (int i = 0; i < 2; ++i) {
#pragma unroll
        for (int j = 0; j < 4; ++j) {
            int col = col0 + n0 + j * 16 + la;
            float bb = bias[col];
#pragma unroll
            for (int r = 0; r < 4; ++r) {
                int row = row0 + m0 + i * 16 + hi * 4 + r;
                float v = acc[i][j][r] + bb;
                if (MODE == 1) {
                    ((bf16_t*)out0v)[(size_t)row * 128 + col] = (bf16_t)v;
                } else if (MODE == 2) {
                    ((float*)out0v)[(size_t)row * 768 + col] = v;
                } else if (MODE == 3) {
                    ((bf16_t*)out0v)[(size_t)row * 128 + col] = (bf16_t)fmaxf(v, 0.f);
                } else {  // MODE 4
                    if (row < Mlimit)
                        ((float*)out0v)[(size_t)row * 128 + col] = v + resid[(size_t)row * 128 + col];
                }
            }
        }
    }
}

// ------------------------------------------------------------------
// CSR build (cnt zeroed by prep2)
// ------------------------------------------------------------------
__global__ void hist_kernel(const int* __restrict__ dst, int* __restrict__ cnt, int E_)
{
    int i = blockIdx.x * THREADS + threadIdx.x;
    if (i < E_) atomicAdd(&cnt[dst[i]], 1);
}

// single-block shfl-based exclusive scan; 1024 threads x 10 elems covers P+1<=10240
__global__ void scan_kernel(const int* __restrict__ cnt, int* __restrict__ offb, int P_)
{
    __shared__ int wsum[16];
    int tid = threadIdx.x;
    int lane = tid & 63, w = tid >> 6;
    int base = tid * 10;
    int c[10];
    int s = 0;
#pragma unroll
    for (int j = 0; j < 10; ++j) {
        int i = base + j;
        c[j] = (i < P_) ? cnt[i] : 0;
        s += c[j];
    }
    int pre = s;
    for (int o = 1; o < 64; o <<= 1) {
        int t = __shfl_up(pre, o);
        if (lane >= o) pre += t;
    }
    if (lane == 63) wsum[w] = pre;
    __syncthreads();
    if (w == 0 && lane < 16) {
        int v = wsum[lane];
        for (int o = 1; o < 16; o <<= 1) {
            int t = __shfl_up(v, o, 16);
            if (lane >= o) v += t;
        }
        wsum[lane] = v;
    }
    __syncthreads();
    int waveoff = (w == 0) ? 0 : wsum[w - 1];
    int run = waveoff + pre - s;
#pragma unroll
    for (int j = 0; j < 10; ++j) {
        int i = base + j;
        if (i <= P_) offb[i] = run;
        run += c[j];
    }
}

// fill: store SRC NODE ID directly
__global__ void fill_src_kernel(const int* __restrict__ dst, const int* __restrict__ src,
                                const int* __restrict__ offb, int* __restrict__ cur,
                                int* __restrict__ csrc, int E_)
{
    int i = blockIdx.x * THREADS + threadIdx.x;
    if (i < E_) {
        int d = dst[i];
        int pos = atomicAdd(&cur[d], 1);
        csrc[offb[d] + pos] = src[i];
    }
}

// ------------------------------------------------------------------
// fused attention + gather + rms/sigmoid gate: 1 wave/particle, 4/block.
// lane = (g=lane>>4 edge-group, c=lane&15 col-chunk). KVb row: K 0..127,
// V 128..255. After cross-group reduce, all lanes hold the row sums ->
// gate computed in-register, AG = [gated | h] bf16 written directly.
// ------------------------------------------------------------------
__global__ __launch_bounds__(256) void edge_kernel(
    const int* __restrict__ offb, const int* __restrict__ csrc,
    const bf16_t* __restrict__ KVb, const bf16_t* __restrict__ Qb,
    const float* __restrict__ ph, const float* __restrict__ rms_w,
    const float* __restrict__ lin_w, bf16_t* __restrict__ AG, int P_)
{
    int tid = threadIdx.x;
    int p = blockIdx.x * 4 + (tid >> 6);
    if (p >= P_) return;
    int lane = tid & 63;
    int c = lane & 15, g = lane >> 4;

    bf16x8 q8 = *(const bf16x8*)(Qb + (size_t)p * 128 + c * 8);
    float qf[8];
#pragma unroll
    for (int j = 0; j < 8; ++j) qf[j] = (float)q8[j];

    int s0 = offb[p], e0 = offb[p + 1];
    float acc[8] = {};

    int i = s0 + g;
    for (; i + 12 < e0; i += 16) {
        int n0 = csrc[i], n1 = csrc[i + 4], n2 = csrc[i + 8], n3 = csrc[i + 12];
        const bf16_t* b0 = KVb + (size_t)n0 * 256 + c * 8;
        const bf16_t* b1 = KVb + (size_t)n1 * 256 + c * 8;
        const bf16_t* b2 = KVb + (size_t)n2 * 256 + c * 8;
        const bf16_t* b3 = KVb + (size_t)n3 * 256 + c * 8;
        bf16x8 k0 = *(const bf16x8*)b0, v0 = *(const bf16x8*)(b0 + 128);
        bf16x8 k1 = *(const bf16x8*)b1, v1 = *(const bf16x8*)(b1 + 128);
        bf16x8 k2 = *(const bf16x8*)b2, v2 = *(const bf16x8*)(b2 + 128);
        bf16x8 k3 = *(const bf16x8*)b3, v3 = *(const bf16x8*)(b3 + 128);
        float d0 = 0.f, d1 = 0.f, d2 = 0.f, d3 = 0.f;
#pragma unroll
        for (int j = 0; j < 8; ++j) {
            d0 += qf[j] * (float)k0[j]; d1 += qf[j] * (float)k1[j];
            d2 += qf[j] * (float)k2[j]; d3 += qf[j] * (float)k3[j];
        }
        d0 += __shfl_xor(d0, 1); d1 += __shfl_xor(d1, 1); d2 += __shfl_xor(d2, 1); d3 += __shfl_xor(d3, 1);
        d0 += __shfl_xor(d0, 2); d1 += __shfl_xor(d1, 2); d2 += __shfl_xor(d2, 2); d3 += __shfl_xor(d3, 2);
        d0 += __shfl_xor(d0, 4); d1 += __shfl_xor(d1, 4); d2 += __shfl_xor(d2, 4); d3 += __shfl_xor(d3, 4);
        d0 += __shfl_xor(d0, 8); d1 += __shfl_xor(d1, 8); d2 += __shfl_xor(d2, 8); d3 += __shfl_xor(d3, 8);
        float a0 = fmaxf(d0 * 0.1f, 0.f), a1 = fmaxf(d1 * 0.1f, 0.f);
        float a2 = fmaxf(d2 * 0.1f, 0.f), a3 = fmaxf(d3 * 0.1f, 0.f);
#pragma unroll
        for (int j = 0; j < 8; ++j)
            acc[j] += a0 * (float)v0[j] + a1 * (float)v1[j]
                    + a2 * (float)v2[j] + a3 * (float)v3[j];
    }
    for (; i < e0; i += 4) {
        int nA = csrc[i];
        const bf16_t* bA = KVb + (size_t)nA * 256 + c * 8;
        bf16x8 kA = *(const bf16x8*)bA;
        bf16x8 vA = *(const bf16x8*)(bA + 128);
        float dA = 0.f;
#pragma unroll
        for (int j = 0; j < 8; ++j) dA += qf[j] * (float)kA[j];
        dA += __shfl_xor(dA, 1);
        dA += __shfl_xor(dA, 2);
        dA += __shfl_xor(dA, 4);
        dA += __shfl_xor(dA, 8);
        float aA = fmaxf(dA * 0.1f, 0.f);
#pragma unroll
        for (int j = 0; j < 8; ++j) acc[j] += aA * (float)vA[j];
    }

    // reduce across the 4 edge-groups; afterwards every lane holds totals
#pragma unroll
    for (int j = 0; j < 8; ++j) {
        acc[j] += __shfl_xor(acc[j], 16);
        acc[j] += __shfl_xor(acc[j], 32);
    }

    // fused rms-norm * sigmoid gate (was gate_kernel)
    float ss = 0.f;
#pragma unroll
    for (int j = 0; j < 8; ++j) ss += acc[j] * acc[j];
    ss += __shfl_xor(ss, 1); ss += __shfl_xor(ss, 2); ss += __shfl_xor(ss, 4); ss += __shfl_xor(ss, 8);
    float scale = rsqrtf(ss * (1.f / 128.f) + 1e-6f);
    if (g == 0) {
        int cb = c * 8;
        const float* hp = ph + (size_t)p * 128 + cb;
        float4 ha = *(const float4*)hp, hb = *(const float4*)(hp + 4);
        float hv[8] = {ha.x, ha.y, ha.z, ha.w, hb.x, hb.y, hb.z, hb.w};
        bf16x8 gv, hvb;
#pragma unroll
        for (int j = 0; j < 8; ++j) {
            float wsv = acc[j];
            float rv = wsv * scale * rms_w[cb + j];
            gv[j] = (bf16_t)(rv * sigmoidf_(wsv * lin_w[cb + j]));
            hvb[j] = (bf16_t)hv[j];
        }
        *(bf16x8*)(AG + (size_t)p * 256 + cb) = gv;
        *(bf16x8*)(AG + (size_t)p * 256 + 128 + cb) = hvb;
    }
}

// ------------------------------------------------------------------
// gru+ln pointwise: read G768 [Mq,768] fp32 (gi|gh), h=ph fp32;
// compute h_new, LayerNorm -> LNb bf16 [Mq,128]
// ------------------------------------------------------------------
__global__ void gru_ln_kernel(const float* __restrict__ G768, const float* __restrict__ ph,
                              const float* __restrict__ ln_g, const float* __restrict__ ln_b,
                              bf16_t* __restrict__ LNb, int P_, int Mq)
{
    int tid = threadIdx.x;
    int g = tid >> 4, s = tid & 15;
    int p = blockIdx.x * 16 + g;
    if (p >= Mq) return;
    int cb = s * 8;
    if (p >= P_) {
        bf16x8 z = {};
        *(bf16x8*)(LNb + (size_t)p * 128 + cb) = z;
        return;
    }
    const float* G = G768 + (size_t)p * 768;
    float ir[8], iz[8], in_[8], hr[8], hz[8], hn_[8], hv[8];
#pragma unroll
    for (int q = 0; q < 2; ++q) {
        float4 v;
        v = *(const float4*)(G + cb + q * 4);        ir[q*4]=v.x; ir[q*4+1]=v.y; ir[q*4+2]=v.z; ir[q*4+3]=v.w;
        v = *(const float4*)(G + 128 + cb + q * 4);  iz[q*4]=v.x; iz[q*4+1]=v.y; iz[q*4+2]=v.z; iz[q*4+3]=v.w;
        v = *(const float4*)(G + 256 + cb + q * 4);  in_[q*4]=v.x; in_[q*4+1]=v.y; in_[q*4+2]=v.z; in_[q*4+3]=v.w;
        v = *(const float4*)(G + 384 + cb + q * 4);  hr[q*4]=v.x; hr[q*4+1]=v.y; hr[q*4+2]=v.z; hr[q*4+3]=v.w;
        v = *(const float4*)(G + 512 + cb + q * 4);  hz[q*4]=v.x; hz[q*4+1]=v.y; hz[q*4+2]=v.z; hz[q*4+3]=v.w;
        v = *(const float4*)(G + 640 + cb + q * 4);  hn_[q*4]=v.x; hn_[q*4+1]=v.y; hn_[q*4+2]=v.z; hn_[q*4+3]=v.w;
        v = *(const float4*)(ph + (size_t)p * 128 + cb + q * 4);
        hv[q*4]=v.x; hv[q*4+1]=v.y; hv[q*4+2]=v.z; hv[q*4+3]=v.w;
    }
    float hn[8];
    float sm = 0.f, sq = 0.f;
#pragma unroll
    for (int j = 0; j < 8; ++j) {
        float r = sigmoidf_(ir[j] + hr[j]);
        float z = sigmoidf_(iz[j] + hz[j]);
        float n = tanhf(in_[j] + r * hn_[j]);
        hn[j] = (1.f - z) * n + z * hv[j];
        sm += hn[j]; sq += hn[j] * hn[j];
    }
    sm += __shfl_xor(sm, 1); sm += __shfl_xor(sm, 2); sm += __shfl_xor(sm, 4); sm += __shfl_xor(sm, 8);
    sq += __shfl_xor(sq, 1); sq += __shfl_xor(sq, 2); sq += __shfl_xor(sq, 4); sq += __shfl_xor(sq, 8);
    float mu = sm * (1.f / 128.f);
    float var = sq * (1.f / 128.f) - mu * mu;
    float iv = rsqrtf(var + 1e-5f);
    bf16x8 o;
#pragma unroll
    for (int j = 0; j < 8; ++j) {
        int c = cb + j;
        o[j] = (bf16_t)((hn[j] - mu) * iv * ln_g[c] + ln_b[c]);
    }
    *(bf16x8*)(LNb + (size_t)p * 128 + cb) = o;
}

// ------------------------------------------------------------------
extern "C" void kernel_launch(void* const* d_in, const int* in_sizes, int n_in,
                              void* d_out, int out_size, void* d_ws, size_t ws_size,
                              hipStream_t stream)
{
    const float* nh      = (const float*)d_in[0];
    const float* energy  = (const float*)d_in[1];
    const float* eta     = (const float*)d_in[2];
    const float* phi     = (const float*)d_in[3];
    const float* layer   = (const float*)d_in[4];
    const float* eta_l   = (const float*)d_in[5];
    const float* phi_l   = (const float*)d_in[6];
    const float* ene_l   = (const float*)d_in[7];
    const float* track   = (const float*)d_in[8];
    const float* ph      = (const float*)d_in[9];
    const float* grep    = (const float*)d_in[10];
    const int*   esrc    = (const int*)d_in[11];
    const int*   edst    = (const int*)d_in[12];
    const float* W_key   = (const float*)d_in[13];
    const float* b_key   = (const float*)d_in[14];
    const float* W_val   = (const float*)d_in[15];
    const float* b_val   = (const float*)d_in[16];
    const float* W_q     = (const float*)d_in[17];
    const float* b_q     = (const float*)d_in[18];
    const float* W_ih    = (const float*)d_in[19];
    const float* b_ih    = (const float*)d_in[20];
    const float* W_hh    = (const float*)d_in[21];
    const float* b_hh    = (const float*)d_in[22];
    const float* ln_g    = (const float*)d_in[23];
    const float* ln_b    = (const float*)d_in[24];
    const float* W1      = (const float*)d_in[25];
    const float* b1      = (const float*)d_in[26];
    const float* W2      = (const float*)d_in[27];
    const float* b2      = (const float*)d_in[28];
    const float* rms_w   = (const float*)d_in[29];
    const float* lin_w   = (const float*)d_in[30];

    const int N = in_sizes[1];
    const int P = in_sizes[9] / 128;
    const int E = in_sizes[11];
    const int Mpad = ((N + 127) / 128) * 128;   // 100096
    const int Mq   = ((P + 127) / 128) * 128;   // 10112

    // workspace layout (byte offsets, 256B aligned)
    char* base = (char*)d_ws;
    size_t off = 0;
    auto alloc = [&](size_t bytes) { void* p = base + off; off = (off + bytes + 255) & ~(size_t)255; return p; };
    bf16_t* skipb = (bf16_t*)alloc((size_t)Mpad * 32 * 2);    // 6.4 MB
    bf16_t* WbfT  = (bf16_t*)alloc(256 * 288 * 2);
    bf16_t* WqT   = (bf16_t*)alloc(128 * 384 * 2);
    float*  bpn   = (float*)alloc(256 * 4);
    float*  bpq   = (float*)alloc(128 * 4);
    bf16_t* KVb   = (bf16_t*)alloc((size_t)Mpad * 256 * 2);   // 51.2 MB interleaved K|V
    bf16_t* Qb    = (bf16_t*)alloc((size_t)Mq * 128 * 2);
    // cnt and cur MUST be contiguous: prep2 zeroes cnt[0..2P)
    int*    cnt   = (int*)alloc((size_t)(2 * P) * 4);
    int*    cur   = cnt + P;
    int*    offb  = (int*)alloc((size_t)(P + 1) * 4);
    int*    csrc  = (int*)alloc((size_t)E * 4);
    // node-update buffers
    bf16_t* AG    = (bf16_t*)alloc((size_t)Mq * 256 * 2);
    bf16_t* BTg   = (bf16_t*)alloc(768 * 256 * 2);
    bf16_t* W1Tp  = (bf16_t*)alloc(128 * 128 * 2);
    bf16_t* W2Tp  = (bf16_t*)alloc(128 * 128 * 2);
    float*  bgru  = (float*)alloc(768 * 4);
    float*  b1p   = (float*)alloc(128 * 4);
    float*  G768  = (float*)alloc((size_t)Mq * 768 * 4);      // 31 MB
    bf16_t* LNb   = (bf16_t*)alloc((size_t)Mq * 128 * 2);
    bf16_t* M1    = (bf16_t*)alloc((size_t)Mq * 128 * 2);

    // 1. weight prep (+ cnt zero + AG pad zero) + skip features
    {
        int total = 256 * 288 + 128 * 384 + 256 + 128;
        prep_kernel<<<(total + THREADS - 1) / THREADS, THREADS, 0, stream>>>(
            W_key, W_val, W_q, b_key, b_val, b_q, WbfT, WqT, bpn, bpq);
        int padElems = (Mq - P) * 256;
        int total2 = 768 * 256 + 128 * 128 + 128 * 128 + 768 + 128 + 2 * P + padElems;
        prep2_kernel<<<(total2 + THREADS - 1) / THREADS, THREADS, 0, stream>>>(
            W_ih, W_hh, b_ih, b_hh, W1, b1, W2, BTg, W1Tp, W2Tp, bgru, b1p,
            cnt, 2 * P, AG, P, padElems);
        skip_kernel<<<(Mpad + THREADS - 1) / THREADS, THREADS, 0, stream>>>(
            energy, eta, phi, layer, eta_l, phi_l, ene_l, track, skipb, N, Mpad);
    }
    // 2. K/V GEMM: register-pipelined direct GEMM; Q GEMM: LDS path
    kv_gemm<<<Mpad / 32, THREADS, 0, stream>>>(nh, skipb, WbfT, bpn, KVb, N);
    mfma_gemm<1><<<dim3(1, Mq / 64), THREADS, 0, stream>>>(
        ph, grep, WqT, bpq, Qb, nullptr, 384, 0, P);
    // 3. CSR build (src ids stored directly)
    hist_kernel<<<(E + THREADS - 1) / THREADS, THREADS, 0, stream>>>(edst, cnt, E);
    scan_kernel<<<1, 1024, 0, stream>>>(cnt, offb, P);
    fill_src_kernel<<<(E + THREADS - 1) / THREADS, THREADS, 0, stream>>>(
        edst, esrc, offb, cur, csrc, E);
    // 4. fused attention + gather + gate -> AG
    edge_kernel<<<(P + 3) / 4, THREADS, 0, stream>>>(
        offb, csrc, KVb, Qb, ph, rms_w, lin_w, AG, P);
    // 5. node update: GRU GEMM -> pointwise+LN -> MLP1 -> MLP2+residual
    mfma_gemm<2><<<dim3(6, Mq / 64), THREADS, 0, stream>>>(
        AG, nullptr, BTg, bgru, G768, nullptr, 256, 0, Mq);
    gru_ln_kernel<<<Mq / 16, THREADS, 0, stream>>>(G768, ph, ln_g, ln_b, LNb, P, Mq);
    mfma_gemm<3><<<dim3(1, Mq / 64), THREADS, 0, stream>>>(
        LNb, nullptr, W1Tp, b1p, M1, nullptr, 128, 0, Mq);
    mfma_gemm<4><<<dim3(1, Mq / 64), THREADS, 0, stream>>>(
        M1, nullptr, W2Tp, b2, d_out, ph, 128, P, Mq);
}

// Round 11
// 226.139 us; speedup vs baseline: 1.1670x; 1.1591x over previous
//
#include <hip/hip_runtime.h>
#include <hip/hip_bf16.h>
#include <math.h>

#define THREADS 256

typedef __bf16 bf16_t;
typedef __bf16 bf16x8 __attribute__((ext_vector_type(8)));
typedef __bf16 bf16x4 __attribute__((ext_vector_type(4)));
typedef float f32x4 __attribute__((ext_vector_type(4)));

__device__ __forceinline__ float sigmoidf_(float x) { return 1.f / (1.f + expf(-x)); }

__device__ __forceinline__ void gload_lds16(const void* g, void* l) {
    __builtin_amdgcn_global_load_lds((const __attribute__((address_space(1))) void*)g,
                                     (__attribute__((address_space(3))) void*)l, 16, 0, 0);
}

__device__ __forceinline__ bf16x8 cvt8(float4 a, float4 b) {
    bf16x8 v;
    v[0] = (bf16_t)a.x; v[1] = (bf16_t)a.y; v[2] = (bf16_t)a.z; v[3] = (bf16_t)a.w;
    v[4] = (bf16_t)b.x; v[5] = (bf16_t)b.y; v[6] = (bf16_t)b.z; v[7] = (bf16_t)b.w;
    return v;
}

// ------------------------------------------------------------------
// prep: pack transposed bf16 weights for key/val/q GEMMs.
// WbfT [256][288], WqT [128][384], bpn[256], bpq[128]
// ------------------------------------------------------------------
__global__ void prep_kernel(const float* __restrict__ W_key, const float* __restrict__ W_val,
                            const float* __restrict__ W_q, const float* __restrict__ b_key,
                            const float* __restrict__ b_val, const float* __restrict__ b_q,
                            bf16_t* __restrict__ WbfT, bf16_t* __restrict__ WqT,
                            float* __restrict__ bpn, float* __restrict__ bpq)
{
    int i = blockIdx.x * THREADS + threadIdx.x;
    const int NW = 256 * 288, NQ = 128 * 384;
    if (i < NW) {
        int c = i / 288, k = i - c * 288;
        float v = 0.f;
        if (k < 283) {
            if (c < 100) v = W_key[k * 100 + c];
            else if (c >= 128 && c < 256) v = W_val[k * 128 + (c - 128)];
        }
        WbfT[i] = (bf16_t)v;
    } else if (i < NW + NQ) {
        int j = i - NW;
        int c = j / 384, k = j - c * 384;
        WqT[j] = (bf16_t)((c < 100) ? W_q[k * 100 + c] : 0.f);
    } else if (i < NW + NQ + 256) {
        int c = i - NW - NQ;
        bpn[c] = (c < 100) ? b_key[c] : ((c >= 128 && c < 256) ? b_val[c - 128] : 0.f);
    } else if (i < NW + NQ + 256 + 128) {
        int c = i - NW - NQ - 256;
        bpq[c] = (c < 100) ? b_q[c] : 0.f;
    }
}

// ------------------------------------------------------------------
// prep2: pack GRU block-diag BTg [768][256], W1Tp [128][128],
// W2Tp [128][128], bgru[768], b1p[128]; PLUS zero cnt[2P] and AG pad rows.
// ------------------------------------------------------------------
__global__ void prep2_kernel(const float* __restrict__ W_ih, const float* __restrict__ W_hh,
                             const float* __restrict__ b_ih, const float* __restrict__ b_hh,
                             const float* __restrict__ W1, const float* __restrict__ b1,
                             const float* __restrict__ W2,
                             bf16_t* __restrict__ BTg, bf16_t* __restrict__ W1Tp,
                             bf16_t* __restrict__ W2Tp, float* __restrict__ bgru,
                             float* __restrict__ b1p,
                             int* __restrict__ cnt, int twoP,
                             bf16_t* __restrict__ AG, int padStart, int padElems)
{
    int i = blockIdx.x * THREADS + threadIdx.x;
    const int NG = 768 * 256, N1 = 128 * 128, N2 = 128 * 128;
    const int NB = NG + N1 + N2 + 768 + 128;
    if (i < NG) {
        int c = i >> 8, k = i & 255;
        float v = 0.f;
        if (c < 384) { if (k < 128) v = W_ih[k * 384 + c]; }
        else         { if (k >= 128) v = W_hh[(k - 128) * 384 + (c - 384)]; }
        BTg[i] = (bf16_t)v;
    } else if (i < NG + N1) {
        int j = i - NG; int c = j >> 7, k = j & 127;
        W1Tp[j] = (bf16_t)((c < 64) ? W1[k * 64 + c] : 0.f);
    } else if (i < NG + N1 + N2) {
        int j = i - NG - N1; int c = j >> 7, k = j & 127;
        W2Tp[j] = (bf16_t)((k < 64) ? W2[k * 128 + c] : 0.f);
    } else if (i < NG + N1 + N2 + 768) {
        int c = i - NG - N1 - N2;
        bgru[c] = (c < 384) ? b_ih[c] : b_hh[c - 384];
    } else if (i < NB) {
        int c = i - NG - N1 - N2 - 768;
        b1p[c] = (c < 64) ? b1[c] : 0.f;
    } else if (i < NB + twoP) {
        cnt[i - NB] = 0;
    } else if (i < NB + twoP + padElems) {
        int j = i - NB - twoP;
        AG[(size_t)padStart * 256 + j] = (bf16_t)0.f;
    }
}

// skip features -> skipb bf16 [Mpad,32] (27 real + 5 zero; pad rows zero)
__global__ void skip_kernel(const float* __restrict__ energy, const float* __restrict__ eta,
                            const float* __restrict__ phi, const float* __restrict__ layer,
                            const float* __restrict__ eta_l, const float* __restrict__ phi_l,
                            const float* __restrict__ ene_l, const float* __restrict__ track,
                            bf16_t* __restrict__ skipb, int N_, int Mpad)
{
    int n = blockIdx.x * THREADS + threadIdx.x;
    if (n >= Mpad) return;
    float o[32];
#pragma unroll
    for (int j = 0; j < 32; ++j) o[j] = 0.f;
    if (n < N_) {
        o[0] = (logf(energy[n]) - 4.0f) * 0.5f;
        o[1] = eta[n] * (1.f / 1.5f);
        o[2] = phi[n];
        o[3] = layer[n];
#pragma unroll
        for (int j = 0; j < 6; ++j) o[4 + j]  = eta_l[n * 6 + j] * (1.f / 1.5f);
#pragma unroll
        for (int j = 0; j < 6; ++j) o[10 + j] = phi_l[n * 6 + j];
#pragma unroll
        for (int j = 0; j < 6; ++j) o[16 + j] = ene_l[n * 6 + j];
#pragma unroll
        for (int j = 0; j < 5; ++j) o[22 + j] = track[n * 5 + j];
    }
    bf16_t* dst = skipb + (size_t)n * 32;
#pragma unroll
    for (int g = 0; g < 4; ++g) {
        bf16x8 v;
#pragma unroll
        for (int j = 0; j < 8; ++j) v[j] = (bf16_t)o[g * 8 + j];
        *(bf16x8*)(dst + g * 8) = v;
    }
}

// ------------------------------------------------------------------
// kv_gemm v3: one-shot COALESCED A staging (full K), then barrier-free
// MFMA loop. Block = 64 rows x 256 cols (A read ONCE), 4 waves each own
// a 64-col slice. Staging: wave w, round r loads row r*4+w as 64 lanes
// x float4 = one contiguous 1KB row per instruction (the convertA access
// shape, ~6 TB/s) -> cvt -> ds_write_b64. ONE __syncthreads total.
// MFMA loop: a-frags from LDS (read-only), b-frags direct from
// L2-resident WbfT (144KB). 16 MFMA : 8 loads per K-step.
// (r8/r9/r10 all paid 16-segment scattered A-reads per K-step: a BK=32
//  fp32 row is only 128B -> never coalesces. Fix = access shape.)
// ------------------------------------------------------------------
__global__ __launch_bounds__(256) void kv_gemm(
    const float* __restrict__ nh, const bf16_t* __restrict__ skipb,
    const bf16_t* __restrict__ BT, const float* __restrict__ bias,
    bf16_t* __restrict__ KVb, int N_)
{
    __shared__ short As[64 * 288];   // [row][k] bf16, 576B rows, 36.9 KB
    int tid = threadIdx.x;
    int w = tid >> 6, lane = tid & 63;
    int la = lane & 15, hi = lane >> 4;
    int row0 = blockIdx.x * 64;
    int col0 = w * 64;

    // ---- stage A cols 0..255: 16 rounds x (4 waves x 1 full row each)
#pragma unroll
    for (int r = 0; r < 16; ++r) {
        int row = r * 4 + w;
        int grow = row0 + row;
        float4 f = make_float4(0.f, 0.f, 0.f, 0.f);
        if (grow < N_) f = *(const float4*)(nh + (size_t)grow * 256 + lane * 4);
        bf16x4 h;
        h[0] = (bf16_t)f.x; h[1] = (bf16_t)f.y; h[2] = (bf16_t)f.z; h[3] = (bf16_t)f.w;
        *(bf16x4*)(As + row * 288 + lane * 4) = h;
    }
    // ---- stage skip tail cols 256..287 (bf16, pad rows pre-zeroed)
    {
        int row = tid >> 2, part = tid & 3;
        bf16x8 s = *(const bf16x8*)(skipb + (size_t)(row0 + row) * 32 + part * 8);
        *(bf16x8*)(As + row * 288 + 256 + part * 8) = s;
    }
    __syncthreads();

    f32x4 zero4 = {0.f, 0.f, 0.f, 0.f};
    f32x4 acc[4][4];
#pragma unroll
    for (int i = 0; i < 4; ++i)
#pragma unroll
        for (int j = 0; j < 4; ++j) acc[i][j] = zero4;

#pragma unroll
    for (int t = 0; t < 9; ++t) {
        int kt = t * 32;
        bf16x8 b[4];
#pragma unroll
        for (int j = 0; j < 4; ++j)
            b[j] = *(const bf16x8*)(BT + (size_t)(col0 + j * 16 + la) * 288 + kt + hi * 8);
        bf16x8 a[4];
#pragma unroll
        for (int i = 0; i < 4; ++i)
            a[i] = *(const bf16x8*)(As + (i * 16 + la) * 288 + kt + hi * 8);
#pragma unroll
        for (int i = 0; i < 4; ++i)
#pragma unroll
            for (int j = 0; j < 4; ++j)
                acc[i][j] = __builtin_amdgcn_mfma_f32_16x16x32_bf16(a[i], b[j], acc[i][j], 0, 0, 0);
    }

#pragma unroll
    for (int j = 0; j < 4; ++j) {
        int col = col0 + j * 16 + la;
        float bb = bias[col];
#pragma unroll
        for (int i = 0; i < 4; ++i) {
#pragma unroll
            for (int r = 0; r < 4; ++r) {
                int row = row0 + i * 16 + hi * 4 + r;
                KVb[(size_t)row * 256 + col] = (bf16_t)(acc[i][j][r] + bb);
            }
        }
    }
}

// ------------------------------------------------------------------
// bf16 MFMA GEMM (modes 1-4, small GEMMs): 64x128 tile, BK=32, 4 waves,
// single-buffered LDS, 2-barrier loop. (r8 structure)
// MODE 1: A = ph fp32 [.,128] | grep fp32 [.,256]; K=384; out Qb bf16
// MODE 2: A bf16 stride K; fp32 out ldc=768   MODE 3: bf16 out + relu
// MODE 4: fp32 out = acc+bias+resid, row<Mlimit
// ------------------------------------------------------------------
template <int MODE>
__global__ __launch_bounds__(256) void mfma_gemm(
    const void* __restrict__ A0, const void* __restrict__ A1,
    const bf16_t* __restrict__ BT, const float* __restrict__ bias,
    void* __restrict__ out0v, const float* __restrict__ resid,
    int K, int Mlimit, int Nrows)
{
    __shared__ short AsS[64 * 32];   // [row][k] bf16, 64B rows
    __shared__ short BsS[128 * 32];  // [col][k]
    int tid = threadIdx.x;
    int lane = tid & 63, w = tid >> 6;
    int la = lane & 15, hi = lane >> 4;
    int m0 = (w & 1) * 32, n0 = (w >> 1) * 64;
    int row0 = blockIdx.y * 64, col0 = blockIdx.x * 128;

    f32x4 zero4 = {0.f, 0.f, 0.f, 0.f};
    f32x4 acc[2][4];
#pragma unroll
    for (int i = 0; i < 2; ++i)
#pragma unroll
        for (int j = 0; j < 4; ++j) acc[i][j] = zero4;

    const int ra = tid >> 2, ka = (tid & 3) * 8;   // A: 1 chunk (16B) / thread
    const int c1 = tid + 256;                       // B: 2 chunks / thread
    const int rb0 = tid >> 2, kb0 = (tid & 3) * 8;
    const int rb1 = c1 >> 2,  kb1 = (c1 & 3) * 8;

    for (int kt = 0; kt < K; kt += 32) {
        int gmA = row0 + ra;
        if (MODE == 1) {
            int gk = kt + ka;
            bf16x8 v = {};
            if (gmA < Nrows) {
                const float* s = (gk < 128) ? ((const float*)A0 + (size_t)gmA * 128 + gk)
                                            : ((const float*)A1 + (size_t)gmA * 256 + (gk - 128));
                v = cvt8(*(const float4*)s, *(const float4*)(s + 4));
            }
            *(bf16x8*)(AsS + (size_t)tid * 8) = v;
        } else {
            gload_lds16((const bf16_t*)A0 + (size_t)gmA * K + kt + ka,
                        AsS + (size_t)tid * 8);
        }
        gload_lds16(BT + (size_t)(col0 + rb0) * K + kt + kb0, BsS + (size_t)tid * 8);
        gload_lds16(BT + (size_t)(col0 + rb1) * K + kt + kb1, BsS + (size_t)c1 * 8);
        __syncthreads();
        bf16x8 a[2], b[4];
#pragma unroll
        for (int i = 0; i < 2; ++i)
            a[i] = *(const bf16x8*)(AsS + (m0 + i * 16 + la) * 32 + hi * 8);
#pragma unroll
        for (int j = 0; j < 4; ++j)
            b[j] = *(const bf16x8*)(BsS + (n0 + j * 16 + la) * 32 + hi * 8);
#pragma unroll
        for (int i = 0; i < 2; ++i)
#pragma unroll
            for (int j = 0; j < 4; ++j)
                acc[i][j] = __builtin_amdgcn_mfma_f32_16x16x32_bf16(a[i], b[j], acc[i][j], 0, 0, 0);
        __syncthreads();
    }

#pragma unroll
    for (int i = 0; i < 2; ++i) {
#pragma unroll
        for (int j = 0; j < 4; ++j) {
            int col = col0 + n0 + j * 16 + la;
            float bb = bias[col];
#pragma unroll
            for (int r = 0; r < 4; ++r) {
                int row = row0 + m0 + i * 16 + hi * 4 + r;
                float v = acc[i][j][r] + bb;
                if (MODE == 1) {
                    ((bf16_t*)out0v)[(size_t)row * 128 + col] = (bf16_t)v;
                } else if (MODE == 2) {
                    ((float*)out0v)[(size_t)row * 768 + col] = v;
                } else if (MODE == 3) {
                    ((bf16_t*)out0v)[(size_t)row * 128 + col] = (bf16_t)fmaxf(v, 0.f);
                } else {  // MODE 4
                    if (row < Mlimit)
                        ((float*)out0v)[(size_t)row * 128 + col] = v + resid[(size_t)row * 128 + col];
                }
            }
        }
    }
}

// ------------------------------------------------------------------
// CSR build (cnt zeroed by prep2)
// ------------------------------------------------------------------
__global__ void hist_kernel(const int* __restrict__ dst, int* __restrict__ cnt, int E_)
{
    int i = blockIdx.x * THREADS + threadIdx.x;
    if (i < E_) atomicAdd(&cnt[dst[i]], 1);
}

// single-block shfl-based exclusive scan; 1024 threads x 10 elems covers P+1<=10240
__global__ void scan_kernel(const int* __restrict__ cnt, int* __restrict__ offb, int P_)
{
    __shared__ int wsum[16];
    int tid = threadIdx.x;
    int lane = tid & 63, w = tid >> 6;
    int base = tid * 10;
    int c[10];
    int s = 0;
#pragma unroll
    for (int j = 0; j < 10; ++j) {
        int i = base + j;
        c[j] = (i < P_) ? cnt[i] : 0;
        s += c[j];
    }
    int pre = s;
    for (int o = 1; o < 64; o <<= 1) {
        int t = __shfl_up(pre, o);
        if (lane >= o) pre += t;
    }
    if (lane == 63) wsum[w] = pre;
    __syncthreads();
    if (w == 0 && lane < 16) {
        int v = wsum[lane];
        for (int o = 1; o < 16; o <<= 1) {
            int t = __shfl_up(v, o, 16);
            if (lane >= o) v += t;
        }
        wsum[lane] = v;
    }
    __syncthreads();
    int waveoff = (w == 0) ? 0 : wsum[w - 1];
    int run = waveoff + pre - s;
#pragma unroll
    for (int j = 0; j < 10; ++j) {
        int i = base + j;
        if (i <= P_) offb[i] = run;
        run += c[j];
    }
}

// fill: store SRC NODE ID directly
__global__ void fill_src_kernel(const int* __restrict__ dst, const int* __restrict__ src,
                                const int* __restrict__ offb, int* __restrict__ cur,
                                int* __restrict__ csrc, int E_)
{
    int i = blockIdx.x * THREADS + threadIdx.x;
    if (i < E_) {
        int d = dst[i];
        int pos = atomicAdd(&cur[d], 1);
        csrc[offb[d] + pos] = src[i];
    }
}

// ------------------------------------------------------------------
// fused attention + gather + rms/sigmoid gate: 1 wave/particle, 4/block.
// lane = (g=lane>>4 edge-group, c=lane&15 col-chunk). KVb row: K 0..127,
// V 128..255. After cross-group reduce, all lanes hold the row sums ->
// gate computed in-register, AG = [gated | h] bf16 written directly.
// ------------------------------------------------------------------
__global__ __launch_bounds__(256) void edge_kernel(
    const int* __restrict__ offb, const int* __restrict__ csrc,
    const bf16_t* __restrict__ KVb, const bf16_t* __restrict__ Qb,
    const float* __restrict__ ph, const float* __restrict__ rms_w,
    const float* __restrict__ lin_w, bf16_t* __restrict__ AG, int P_)
{
    int tid = threadIdx.x;
    int p = blockIdx.x * 4 + (tid >> 6);
    if (p >= P_) return;
    int lane = tid & 63;
    int c = lane & 15, g = lane >> 4;

    bf16x8 q8 = *(const bf16x8*)(Qb + (size_t)p * 128 + c * 8);
    float qf[8];
#pragma unroll
    for (int j = 0; j < 8; ++j) qf[j] = (float)q8[j];

    int s0 = offb[p], e0 = offb[p + 1];
    float acc[8] = {};

    int i = s0 + g;
    for (; i + 12 < e0; i += 16) {
        int n0 = csrc[i], n1 = csrc[i + 4], n2 = csrc[i + 8], n3 = csrc[i + 12];
        const bf16_t* b0 = KVb + (size_t)n0 * 256 + c * 8;
        const bf16_t* b1 = KVb + (size_t)n1 * 256 + c * 8;
        const bf16_t* b2 = KVb + (size_t)n2 * 256 + c * 8;
        const bf16_t* b3 = KVb + (size_t)n3 * 256 + c * 8;
        bf16x8 k0 = *(const bf16x8*)b0, v0 = *(const bf16x8*)(b0 + 128);
        bf16x8 k1 = *(const bf16x8*)b1, v1 = *(const bf16x8*)(b1 + 128);
        bf16x8 k2 = *(const bf16x8*)b2, v2 = *(const bf16x8*)(b2 + 128);
        bf16x8 k3 = *(const bf16x8*)b3, v3 = *(const bf16x8*)(b3 + 128);
        float d0 = 0.f, d1 = 0.f, d2 = 0.f, d3 = 0.f;
#pragma unroll
        for (int j = 0; j < 8; ++j) {
            d0 += qf[j] * (float)k0[j]; d1 += qf[j] * (float)k1[j];
            d2 += qf[j] * (float)k2[j]; d3 += qf[j] * (float)k3[j];
        }
        d0 += __shfl_xor(d0, 1); d1 += __shfl_xor(d1, 1); d2 += __shfl_xor(d2, 1); d3 += __shfl_xor(d3, 1);
        d0 += __shfl_xor(d0, 2); d1 += __shfl_xor(d1, 2); d2 += __shfl_xor(d2, 2); d3 += __shfl_xor(d3, 2);
        d0 += __shfl_xor(d0, 4); d1 += __shfl_xor(d1, 4); d2 += __shfl_xor(d2, 4); d3 += __shfl_xor(d3, 4);
        d0 += __shfl_xor(d0, 8); d1 += __shfl_xor(d1, 8); d2 += __shfl_xor(d2, 8); d3 += __shfl_xor(d3, 8);
        float a0 = fmaxf(d0 * 0.1f, 0.f), a1 = fmaxf(d1 * 0.1f, 0.f);
        float a2 = fmaxf(d2 * 0.1f, 0.f), a3 = fmaxf(d3 * 0.1f, 0.f);
#pragma unroll
        for (int j = 0; j < 8; ++j)
            acc[j] += a0 * (float)v0[j] + a1 * (float)v1[j]
                    + a2 * (float)v2[j] + a3 * (float)v3[j];
    }
    for (; i < e0; i += 4) {
        int nA = csrc[i];
        const bf16_t* bA = KVb + (size_t)nA * 256 + c * 8;
        bf16x8 kA = *(const bf16x8*)bA;
        bf16x8 vA = *(const bf16x8*)(bA + 128);
        float dA = 0.f;
#pragma unroll
        for (int j = 0; j < 8; ++j) dA += qf[j] * (float)kA[j];
        dA += __shfl_xor(dA, 1);
        dA += __shfl_xor(dA, 2);
        dA += __shfl_xor(dA, 4);
        dA += __shfl_xor(dA, 8);
        float aA = fmaxf(dA * 0.1f, 0.f);
#pragma unroll
        for (int j = 0; j < 8; ++j) acc[j] += aA * (float)vA[j];
    }

    // reduce across the 4 edge-groups; afterwards every lane holds totals
#pragma unroll
    for (int j = 0; j < 8; ++j) {
        acc[j] += __shfl_xor(acc[j], 16);
        acc[j] += __shfl_xor(acc[j], 32);
    }

    // fused rms-norm * sigmoid gate (was gate_kernel)
    float ss = 0.f;
#pragma unroll
    for (int j = 0; j < 8; ++j) ss += acc[j] * acc[j];
    ss += __shfl_xor(ss, 1); ss += __shfl_xor(ss, 2); ss += __shfl_xor(ss, 4); ss += __shfl_xor(ss, 8);
    float scale = rsqrtf(ss * (1.f / 128.f) + 1e-6f);
    if (g == 0) {
        int cb = c * 8;
        const float* hp = ph + (size_t)p * 128 + cb;
        float4 ha = *(const float4*)hp, hb = *(const float4*)(hp + 4);
        float hv[8] = {ha.x, ha.y, ha.z, ha.w, hb.x, hb.y, hb.z, hb.w};
        bf16x8 gv, hvb;
#pragma unroll
        for (int j = 0; j < 8; ++j) {
            float wsv = acc[j];
            float rv = wsv * scale * rms_w[cb + j];
            gv[j] = (bf16_t)(rv * sigmoidf_(wsv * lin_w[cb + j]));
            hvb[j] = (bf16_t)hv[j];
        }
        *(bf16x8*)(AG + (size_t)p * 256 + cb) = gv;
        *(bf16x8*)(AG + (size_t)p * 256 + 128 + cb) = hvb;
    }
}

// ------------------------------------------------------------------
// gru+ln pointwise: read G768 [Mq,768] fp32 (gi|gh), h=ph fp32;
// compute h_new, LayerNorm -> LNb bf16 [Mq,128]
// ------------------------------------------------------------------
__global__ void gru_ln_kernel(const float* __restrict__ G768, const float* __restrict__ ph,
                              const float* __restrict__ ln_g, const float* __restrict__ ln_b,
                              bf16_t* __restrict__ LNb, int P_, int Mq)
{
    int tid = threadIdx.x;
    int g = tid >> 4, s = tid & 15;
    int p = blockIdx.x * 16 + g;
    if (p >= Mq) return;
    int cb = s * 8;
    if (p >= P_) {
        bf16x8 z = {};
        *(bf16x8*)(LNb + (size_t)p * 128 + cb) = z;
        return;
    }
    const float* G = G768 + (size_t)p * 768;
    float ir[8], iz[8], in_[8], hr[8], hz[8], hn_[8], hv[8];
#pragma unroll
    for (int q = 0; q < 2; ++q) {
        float4 v;
        v = *(const float4*)(G + cb + q * 4);        ir[q*4]=v.x; ir[q*4+1]=v.y; ir[q*4+2]=v.z; ir[q*4+3]=v.w;
        v = *(const float4*)(G + 128 + cb + q * 4);  iz[q*4]=v.x; iz[q*4+1]=v.y; iz[q*4+2]=v.z; iz[q*4+3]=v.w;
        v = *(const float4*)(G + 256 + cb + q * 4);  in_[q*4]=v.x; in_[q*4+1]=v.y; in_[q*4+2]=v.z; in_[q*4+3]=v.w;
        v = *(const float4*)(G + 384 + cb + q * 4);  hr[q*4]=v.x; hr[q*4+1]=v.y; hr[q*4+2]=v.z; hr[q*4+3]=v.w;
        v = *(const float4*)(G + 512 + cb + q * 4);  hz[q*4]=v.x; hz[q*4+1]=v.y; hz[q*4+2]=v.z; hz[q*4+3]=v.w;
        v = *(const float4*)(G + 640 + cb + q * 4);  hn_[q*4]=v.x; hn_[q*4+1]=v.y; hn_[q*4+2]=v.z; hn_[q*4+3]=v.w;
        v = *(const float4*)(ph + (size_t)p * 128 + cb + q * 4);
        hv[q*4]=v.x; hv[q*4+1]=v.y; hv[q*4+2]=v.z; hv[q*4+3]=v.w;
    }
    float hn[8];
    float sm = 0.f, sq = 0.f;
#pragma unroll
    for (int j = 0; j < 8; ++j) {
        float r = sigmoidf_(ir[j] + hr[j]);
        float z = sigmoidf_(iz[j] + hz[j]);
        float n = tanhf(in_[j] + r * hn_[j]);
        hn[j] = (1.f - z) * n + z * hv[j];
        sm += hn[j]; sq += hn[j] * hn[j];
    }
    sm += __shfl_xor(sm, 1); sm += __shfl_xor(sm, 2); sm += __shfl_xor(sm, 4); sm += __shfl_xor(sm, 8);
    sq += __shfl_xor(sq, 1); sq += __shfl_xor(sq, 2); sq += __shfl_xor(sq, 4); sq += __shfl_xor(sq, 8);
    float mu = sm * (1.f / 128.f);
    float var = sq * (1.f / 128.f) - mu * mu;
    float iv = rsqrtf(var + 1e-5f);
    bf16x8 o;
#pragma unroll
    for (int j = 0; j < 8; ++j) {
        int c = cb + j;
        o[j] = (bf16_t)((hn[j] - mu) * iv * ln_g[c] + ln_b[c]);
    }
    *(bf16x8*)(LNb + (size_t)p * 128 + cb) = o;
}

// ------------------------------------------------------------------
extern "C" void kernel_launch(void* const* d_in, const int* in_sizes, int n_in,
                              void* d_out, int out_size, void* d_ws, size_t ws_size,
                              hipStream_t stream)
{
    const float* nh      = (const float*)d_in[0];
    const float* energy  = (const float*)d_in[1];
    const float* eta     = (const float*)d_in[2];
    const float* phi     = (const float*)d_in[3];
    const float* layer   = (const float*)d_in[4];
    const float* eta_l   = (const float*)d_in[5];
    const float* phi_l   = (const float*)d_in[6];
    const float* ene_l   = (const float*)d_in[7];
    const float* track   = (const float*)d_in[8];
    const float* ph      = (const float*)d_in[9];
    const float* grep    = (const float*)d_in[10];
    const int*   esrc    = (const int*)d_in[11];
    const int*   edst    = (const int*)d_in[12];
    const float* W_key   = (const float*)d_in[13];
    const float* b_key   = (const float*)d_in[14];
    const float* W_val   = (const float*)d_in[15];
    const float* b_val   = (const float*)d_in[16];
    const float* W_q     = (const float*)d_in[17];
    const float* b_q     = (const float*)d_in[18];
    const float* W_ih    = (const float*)d_in[19];
    const float* b_ih    = (const float*)d_in[20];
    const float* W_hh    = (const float*)d_in[21];
    const float* b_hh    = (const float*)d_in[22];
    const float* ln_g    = (const float*)d_in[23];
    const float* ln_b    = (const float*)d_in[24];
    const float* W1      = (const float*)d_in[25];
    const float* b1      = (const float*)d_in[26];
    const float* W2      = (const float*)d_in[27];
    const float* b2      = (const float*)d_in[28];
    const float* rms_w   = (const float*)d_in[29];
    const float* lin_w   = (const float*)d_in[30];

    const int N = in_sizes[1];
    const int P = in_sizes[9] / 128;
    const int E = in_sizes[11];
    const int Mpad = ((N + 127) / 128) * 128;   // 100096
    const int Mq   = ((P + 127) / 128) * 128;   // 10112

    // workspace layout (byte offsets, 256B aligned)
    char* base = (char*)d_ws;
    size_t off = 0;
    auto alloc = [&](size_t bytes) { void* p = base + off; off = (off + bytes + 255) & ~(size_t)255; return p; };
    bf16_t* skipb = (bf16_t*)alloc((size_t)Mpad * 32 * 2);    // 6.4 MB
    bf16_t* WbfT  = (bf16_t*)alloc(256 * 288 * 2);
    bf16_t* WqT   = (bf16_t*)alloc(128 * 384 * 2);
    float*  bpn   = (float*)alloc(256 * 4);
    float*  bpq   = (float*)alloc(128 * 4);
    bf16_t* KVb   = (bf16_t*)alloc((size_t)Mpad * 256 * 2);   // 51.2 MB interleaved K|V
    bf16_t* Qb    = (bf16_t*)alloc((size_t)Mq * 128 * 2);
    // cnt and cur MUST be contiguous: prep2 zeroes cnt[0..2P)
    int*    cnt   = (int*)alloc((size_t)(2 * P) * 4);
    int*    cur   = cnt + P;
    int*    offb  = (int*)alloc((size_t)(P + 1) * 4);
    int*    csrc  = (int*)alloc((size_t)E * 4);
    // node-update buffers
    bf16_t* AG    = (bf16_t*)alloc((size_t)Mq * 256 * 2);
    bf16_t* BTg   = (bf16_t*)alloc(768 * 256 * 2);
    bf16_t* W1Tp  = (bf16_t*)alloc(128 * 128 * 2);
    bf16_t* W2Tp  = (bf16_t*)alloc(128 * 128 * 2);
    float*  bgru  = (float*)alloc(768 * 4);
    float*  b1p   = (float*)alloc(128 * 4);
    float*  G768  = (float*)alloc((size_t)Mq * 768 * 4);      // 31 MB
    bf16_t* LNb   = (bf16_t*)alloc((size_t)Mq * 128 * 2);
    bf16_t* M1    = (bf16_t*)alloc((size_t)Mq * 128 * 2);

    // 1. weight prep (+ cnt zero + AG pad zero) + skip features
    {
        int total = 256 * 288 + 128 * 384 + 256 + 128;
        prep_kernel<<<(total + THREADS - 1) / THREADS, THREADS, 0, stream>>>(
            W_key, W_val, W_q, b_key, b_val, b_q, WbfT, WqT, bpn, bpq);
        int padElems = (Mq - P) * 256;
        int total2 = 768 * 256 + 128 * 128 + 128 * 128 + 768 + 128 + 2 * P + padElems;
        prep2_kernel<<<(total2 + THREADS - 1) / THREADS, THREADS, 0, stream>>>(
            W_ih, W_hh, b_ih, b_hh, W1, b1, W2, BTg, W1Tp, W2Tp, bgru, b1p,
            cnt, 2 * P, AG, P, padElems);
        skip_kernel<<<(Mpad + THREADS - 1) / THREADS, THREADS, 0, stream>>>(
            energy, eta, phi, layer, eta_l, phi_l, ene_l, track, skipb, N, Mpad);
    }
    // 2. K/V GEMM: coalesced-stage + barrier-free MFMA; Q GEMM: LDS path
    kv_gemm<<<Mpad / 64, THREADS, 0, stream>>>(nh, skipb, WbfT, bpn, KVb, N);
    mfma_gemm<1><<<dim3(1, Mq / 64), THREADS, 0, stream>>>(
        ph, grep, WqT, bpq, Qb, nullptr, 384, 0, P);
    // 3. CSR build (src ids stored directly)
    hist_kernel<<<(E + THREADS - 1) / THREADS, THREADS, 0, stream>>>(edst, cnt, E);
    scan_kernel<<<1, 1024, 0, stream>>>(cnt, offb, P);
    fill_src_kernel<<<(E + THREADS - 1) / THREADS, THREADS, 0, stream>>>(
        edst, esrc, offb, cur, csrc, E);
    // 4. fused attention + gather + gate -> AG
    edge_kernel<<<(P + 3) / 4, THREADS, 0, stream>>>(
        offb, csrc, KVb, Qb, ph, rms_w, lin_w, AG, P);
    // 5. node update: GRU GEMM -> pointwise+LN -> MLP1 -> MLP2+residual
    mfma_gemm<2><<<dim3(6, Mq / 64), THREADS, 0, stream>>>(
        AG, nullptr, BTg, bgru, G768, nullptr, 256, 0, Mq);
    gru_ln_kernel<<<Mq / 16, THREADS, 0, stream>>>(G768, ph, ln_g, ln_b, LNb, P, Mq);
    mfma_gemm<3><<<dim3(1, Mq / 64), THREADS, 0, stream>>>(
        LNb, nullptr, W1Tp, b1p, M1, nullptr, 128, 0, Mq);
    mfma_gemm<4><<<dim3(1, Mq / 64), THREADS, 0, stream>>>(
        M1, nullptr, W2Tp, b2, d_out, ph, 128, P, Mq);
}

// Round 12
// 224.435 us; speedup vs baseline: 1.1759x; 1.0076x over previous
//
#include <hip/hip_runtime.h>
#include <hip/hip_bf16.h>
#include <math.h>

#define THREADS 256

typedef __bf16 bf16_t;
typedef __bf16 bf16x8 __attribute__((ext_vector_type(8)));
typedef __bf16 bf16x4 __attribute__((ext_vector_type(4)));
typedef float f32x4 __attribute__((ext_vector_type(4)));

__device__ __forceinline__ float sigmoidf_(float x) { return 1.f / (1.f + expf(-x)); }

__device__ __forceinline__ void gload_lds16(const void* g, void* l) {
    __builtin_amdgcn_global_load_lds((const __attribute__((address_space(1))) void*)g,
                                     (__attribute__((address_space(3))) void*)l, 16, 0, 0);
}

__device__ __forceinline__ bf16x8 cvt8(float4 a, float4 b) {
    bf16x8 v;
    v[0] = (bf16_t)a.x; v[1] = (bf16_t)a.y; v[2] = (bf16_t)a.z; v[3] = (bf16_t)a.w;
    v[4] = (bf16_t)b.x; v[5] = (bf16_t)b.y; v[6] = (bf16_t)b.z; v[7] = (bf16_t)b.w;
    return v;
}

// ------------------------------------------------------------------
// prep: pack transposed bf16 weights for key/val/q GEMMs.
// WbfT [256][288], WqT [128][384], bpn[256], bpq[128]
// ------------------------------------------------------------------
__global__ void prep_kernel(const float* __restrict__ W_key, const float* __restrict__ W_val,
                            const float* __restrict__ W_q, const float* __restrict__ b_key,
                            const float* __restrict__ b_val, const float* __restrict__ b_q,
                            bf16_t* __restrict__ WbfT, bf16_t* __restrict__ WqT,
                            float* __restrict__ bpn, float* __restrict__ bpq)
{
    int i = blockIdx.x * THREADS + threadIdx.x;
    const int NW = 256 * 288, NQ = 128 * 384;
    if (i < NW) {
        int c = i / 288, k = i - c * 288;
        float v = 0.f;
        if (k < 283) {
            if (c < 100) v = W_key[k * 100 + c];
            else if (c >= 128 && c < 256) v = W_val[k * 128 + (c - 128)];
        }
        WbfT[i] = (bf16_t)v;
    } else if (i < NW + NQ) {
        int j = i - NW;
        int c = j / 384, k = j - c * 384;
        WqT[j] = (bf16_t)((c < 100) ? W_q[k * 100 + c] : 0.f);
    } else if (i < NW + NQ + 256) {
        int c = i - NW - NQ;
        bpn[c] = (c < 100) ? b_key[c] : ((c >= 128 && c < 256) ? b_val[c - 128] : 0.f);
    } else if (i < NW + NQ + 256 + 128) {
        int c = i - NW - NQ - 256;
        bpq[c] = (c < 100) ? b_q[c] : 0.f;
    }
}

// ------------------------------------------------------------------
// prep3: repack WbfT into FRAGMENT-ORDER Bpack so kv_gemm's b-frag loads
// are fully coalesced: Bpack[((w*9+t)*4+j)*512 + lane*8 + c] =
// WbfT[(w*64+j*16+(lane&15))*288 + t*32 + (lane>>4)*8 + c].
// One b-frag load = one contiguous 1KB wave-read (was 16-segment scatter).
// ------------------------------------------------------------------
__global__ void prep3_kernel(const bf16_t* __restrict__ WbfT, bf16_t* __restrict__ Bpack)
{
    int i = blockIdx.x * THREADS + threadIdx.x;
    const int TOT = 4 * 9 * 4 * 512;  // 73728
    if (i >= TOT) return;
    int frag = i >> 9, e = i & 511;
    int l = e >> 3, c8 = e & 7;
    int w = frag / 36, rem = frag - w * 36;
    int t = rem >> 2, j = rem & 3;
    int la = l & 15, hi = l >> 4;
    int col = w * 64 + j * 16 + la;
    int k = t * 32 + hi * 8 + c8;
    Bpack[i] = WbfT[col * 288 + k];
}

// ------------------------------------------------------------------
// prep2: pack GRU block-diag BTg [768][256], W1Tp [128][128],
// W2Tp [128][128], bgru[768], b1p[128]; PLUS zero cnt[2P] and AG pad rows.
// ------------------------------------------------------------------
__global__ void prep2_kernel(const float* __restrict__ W_ih, const float* __restrict__ W_hh,
                             const float* __restrict__ b_ih, const float* __restrict__ b_hh,
                             const float* __restrict__ W1, const float* __restrict__ b1,
                             const float* __restrict__ W2,
                             bf16_t* __restrict__ BTg, bf16_t* __restrict__ W1Tp,
                             bf16_t* __restrict__ W2Tp, float* __restrict__ bgru,
                             float* __restrict__ b1p,
                             int* __restrict__ cnt, int twoP,
                             bf16_t* __restrict__ AG, int padStart, int padElems)
{
    int i = blockIdx.x * THREADS + threadIdx.x;
    const int NG = 768 * 256, N1 = 128 * 128, N2 = 128 * 128;
    const int NB = NG + N1 + N2 + 768 + 128;
    if (i < NG) {
        int c = i >> 8, k = i & 255;
        float v = 0.f;
        if (c < 384) { if (k < 128) v = W_ih[k * 384 + c]; }
        else         { if (k >= 128) v = W_hh[(k - 128) * 384 + (c - 384)]; }
        BTg[i] = (bf16_t)v;
    } else if (i < NG + N1) {
        int j = i - NG; int c = j >> 7, k = j & 127;
        W1Tp[j] = (bf16_t)((c < 64) ? W1[k * 64 + c] : 0.f);
    } else if (i < NG + N1 + N2) {
        int j = i - NG - N1; int c = j >> 7, k = j & 127;
        W2Tp[j] = (bf16_t)((k < 64) ? W2[k * 128 + c] : 0.f);
    } else if (i < NG + N1 + N2 + 768) {
        int c = i - NG - N1 - N2;
        bgru[c] = (c < 384) ? b_ih[c] : b_hh[c - 384];
    } else if (i < NB) {
        int c = i - NG - N1 - N2 - 768;
        b1p[c] = (c < 64) ? b1[c] : 0.f;
    } else if (i < NB + twoP) {
        cnt[i - NB] = 0;
    } else if (i < NB + twoP + padElems) {
        int j = i - NB - twoP;
        AG[(size_t)padStart * 256 + j] = (bf16_t)0.f;
    }
}

// skip features -> skipb bf16 [Mpad,32] (27 real + 5 zero; pad rows zero)
__global__ void skip_kernel(const float* __restrict__ energy, const float* __restrict__ eta,
                            const float* __restrict__ phi, const float* __restrict__ layer,
                            const float* __restrict__ eta_l, const float* __restrict__ phi_l,
                            const float* __restrict__ ene_l, const float* __restrict__ track,
                            bf16_t* __restrict__ skipb, int N_, int Mpad)
{
    int n = blockIdx.x * THREADS + threadIdx.x;
    if (n >= Mpad) return;
    float o[32];
#pragma unroll
    for (int j = 0; j < 32; ++j) o[j] = 0.f;
    if (n < N_) {
        o[0] = (logf(energy[n]) - 4.0f) * 0.5f;
        o[1] = eta[n] * (1.f / 1.5f);
        o[2] = phi[n];
        o[3] = layer[n];
#pragma unroll
        for (int j = 0; j < 6; ++j) o[4 + j]  = eta_l[n * 6 + j] * (1.f / 1.5f);
#pragma unroll
        for (int j = 0; j < 6; ++j) o[10 + j] = phi_l[n * 6 + j];
#pragma unroll
        for (int j = 0; j < 6; ++j) o[16 + j] = ene_l[n * 6 + j];
#pragma unroll
        for (int j = 0; j < 5; ++j) o[22 + j] = track[n * 5 + j];
    }
    bf16_t* dst = skipb + (size_t)n * 32;
#pragma unroll
    for (int g = 0; g < 4; ++g) {
        bf16x8 v;
#pragma unroll
        for (int j = 0; j < 8; ++j) v[j] = (bf16_t)o[g * 8 + j];
        *(bf16x8*)(dst + g * 8) = v;
    }
}

// ------------------------------------------------------------------
// kv_gemm v4: r11 structure + (a) fragment-order Bpack -> coalesced 1KB
// b-frag loads, (b) As stride 296 (148 dwords, 148%32=20) -> bank
// conflicts ~2-way (free). 64 rows x 256 cols, 4 waves, 1 barrier.
// ------------------------------------------------------------------
__global__ __launch_bounds__(256) void kv_gemm(
    const float* __restrict__ nh, const bf16_t* __restrict__ skipb,
    const bf16_t* __restrict__ Bpack, const float* __restrict__ bias,
    bf16_t* __restrict__ KVb, int N_)
{
    const int LD = 296;              // padded row stride (bf16)
    __shared__ short As[64 * 296];   // 37.9 KB -> 4 blocks/CU
    int tid = threadIdx.x;
    int w = tid >> 6, lane = tid & 63;
    int la = lane & 15, hi = lane >> 4;
    int row0 = blockIdx.x * 64;
    int col0 = w * 64;

    // ---- stage A cols 0..255: 16 rounds x (4 waves x 1 full 1KB row each)
#pragma unroll
    for (int r = 0; r < 16; ++r) {
        int row = r * 4 + w;
        int grow = row0 + row;
        float4 f = make_float4(0.f, 0.f, 0.f, 0.f);
        if (grow < N_) f = *(const float4*)(nh + (size_t)grow * 256 + lane * 4);
        bf16x4 h;
        h[0] = (bf16_t)f.x; h[1] = (bf16_t)f.y; h[2] = (bf16_t)f.z; h[3] = (bf16_t)f.w;
        *(bf16x4*)(As + row * LD + lane * 4) = h;
    }
    // ---- stage skip tail cols 256..287 (bf16, pad rows pre-zeroed)
    {
        int row = tid >> 2, part = tid & 3;
        bf16x8 s = *(const bf16x8*)(skipb + (size_t)(row0 + row) * 32 + part * 8);
        *(bf16x8*)(As + row * LD + 256 + part * 8) = s;
    }
    __syncthreads();

    f32x4 zero4 = {0.f, 0.f, 0.f, 0.f};
    f32x4 acc[4][4];
#pragma unroll
    for (int i = 0; i < 4; ++i)
#pragma unroll
        for (int j = 0; j < 4; ++j) acc[i][j] = zero4;

    const bf16_t* bp = Bpack + (size_t)(w * 9) * 4 * 512 + lane * 8;
#pragma unroll
    for (int t = 0; t < 9; ++t) {
        int kt = t * 32;
        bf16x8 b[4];
#pragma unroll
        for (int j = 0; j < 4; ++j)
            b[j] = *(const bf16x8*)(bp + (size_t)(t * 4 + j) * 512);
        bf16x8 a[4];
#pragma unroll
        for (int i = 0; i < 4; ++i)
            a[i] = *(const bf16x8*)(As + (i * 16 + la) * LD + kt + hi * 8);
#pragma unroll
        for (int i = 0; i < 4; ++i)
#pragma unroll
            for (int j = 0; j < 4; ++j)
                acc[i][j] = __builtin_amdgcn_mfma_f32_16x16x32_bf16(a[i], b[j], acc[i][j], 0, 0, 0);
    }

#pragma unroll
    for (int j = 0; j < 4; ++j) {
        int col = col0 + j * 16 + la;
        float bb = bias[col];
#pragma unroll
        for (int i = 0; i < 4; ++i) {
#pragma unroll
            for (int r = 0; r < 4; ++r) {
                int row = row0 + i * 16 + hi * 4 + r;
                KVb[(size_t)row * 256 + col] = (bf16_t)(acc[i][j][r] + bb);
            }
        }
    }
}

// ------------------------------------------------------------------
// bf16 MFMA GEMM (modes 1-4, small GEMMs): 64x128 tile, BK=32, 4 waves,
// single-buffered LDS, 2-barrier loop. (r8 structure)
// MODE 1: A = ph fp32 [.,128] | grep fp32 [.,256]; K=384; out Qb bf16
// MODE 2: A bf16 stride K; fp32 out ldc=768   MODE 3: bf16 out + relu
// MODE 4: fp32 out = acc+bias+resid, row<Mlimit
// ------------------------------------------------------------------
template <int MODE>
__global__ __launch_bounds__(256) void mfma_gemm(
    const void* __restrict__ A0, const void* __restrict__ A1,
    const bf16_t* __restrict__ BT, const float* __restrict__ bias,
    void* __restrict__ out0v, const float* __restrict__ resid,
    int K, int Mlimit, int Nrows)
{
    __shared__ short AsS[64 * 32];   // [row][k] bf16, 64B rows
    __shared__ short BsS[128 * 32];  // [col][k]
    int tid = threadIdx.x;
    int lane = tid & 63, w = tid >> 6;
    int la = lane & 15, hi = lane >> 4;
    int m0 = (w & 1) * 32, n0 = (w >> 1) * 64;
    int row0 = blockIdx.y * 64, col0 = blockIdx.x * 128;

    f32x4 zero4 = {0.f, 0.f, 0.f, 0.f};
    f32x4 acc[2][4];
#pragma unroll
    for (int i = 0; i < 2; ++i)
#pragma unroll
        for (int j = 0; j < 4; ++j) acc[i][j] = zero4;

    const int ra = tid >> 2, ka = (tid & 3) * 8;   // A: 1 chunk (16B) / thread
    const int c1 = tid + 256;                       // B: 2 chunks / thread
    const int rb0 = tid >> 2, kb0 = (tid & 3) * 8;
    const int rb1 = c1 >> 2,  kb1 = (c1 & 3) * 8;

    for (int kt = 0; kt < K; kt += 32) {
        int gmA = row0 + ra;
        if (MODE == 1) {
            int gk = kt + ka;
            bf16x8 v = {};
            if (gmA < Nrows) {
                const float* s = (gk < 128) ? ((const float*)A0 + (size_t)gmA * 128 + gk)
                                            : ((const float*)A1 + (size_t)gmA * 256 + (gk - 128));
                v = cvt8(*(const float4*)s, *(const float4*)(s + 4));
            }
            *(bf16x8*)(AsS + (size_t)tid * 8) = v;
        } else {
            gload_lds16((const bf16_t*)A0 + (size_t)gmA * K + kt + ka,
                        AsS + (size_t)tid * 8);
        }
        gload_lds16(BT + (size_t)(col0 + rb0) * K + kt + kb0, BsS + (size_t)tid * 8);
        gload_lds16(BT + (size_t)(col0 + rb1) * K + kt + kb1, BsS + (size_t)c1 * 8);
        __syncthreads();
        bf16x8 a[2], b[4];
#pragma unroll
        for (int i = 0; i < 2; ++i)
            a[i] = *(const bf16x8*)(AsS + (m0 + i * 16 + la) * 32 + hi * 8);
#pragma unroll
        for (int j = 0; j < 4; ++j)
            b[j] = *(const bf16x8*)(BsS + (n0 + j * 16 + la) * 32 + hi * 8);
#pragma unroll
        for (int i = 0; i < 2; ++i)
#pragma unroll
            for (int j = 0; j < 4; ++j)
                acc[i][j] = __builtin_amdgcn_mfma_f32_16x16x32_bf16(a[i], b[j], acc[i][j], 0, 0, 0);
        __syncthreads();
    }

#pragma unroll
    for (int i = 0; i < 2; ++i) {
#pragma unroll
        for (int j = 0; j < 4; ++j) {
            int col = col0 + n0 + j * 16 + la;
            float bb = bias[col];
#pragma unroll
            for (int r = 0; r < 4; ++r) {
                int row = row0 + m0 + i * 16 + hi * 4 + r;
                float v = acc[i][j][r] + bb;
                if (MODE == 1) {
                    ((bf16_t*)out0v)[(size_t)row * 128 + col] = (bf16_t)v;
                } else if (MODE == 2) {
                    ((float*)out0v)[(size_t)row * 768 + col] = v;
                } else if (MODE == 3) {
                    ((bf16_t*)out0v)[(size_t)row * 128 + col] = (bf16_t)fmaxf(v, 0.f);
                } else {  // MODE 4
                    if (row < Mlimit)
                        ((float*)out0v)[(size_t)row * 128 + col] = v + resid[(size_t)row * 128 + col];
                }
            }
        }
    }
}

// ------------------------------------------------------------------
// CSR build (cnt zeroed by prep2)
// ------------------------------------------------------------------
__global__ void hist_kernel(const int* __restrict__ dst, int* __restrict__ cnt, int E_)
{
    int i = blockIdx.x * THREADS + threadIdx.x;
    if (i < E_) atomicAdd(&cnt[dst[i]], 1);
}

// single-block shfl-based exclusive scan; 1024 threads x 10 elems covers P+1<=10240
__global__ void scan_kernel(const int* __restrict__ cnt, int* __restrict__ offb, int P_)
{
    __shared__ int wsum[16];
    int tid = threadIdx.x;
    int lane = tid & 63, w = tid >> 6;
    int base = tid * 10;
    int c[10];
    int s = 0;
#pragma unroll
    for (int j = 0; j < 10; ++j) {
        int i = base + j;
        c[j] = (i < P_) ? cnt[i] : 0;
        s += c[j];
    }
    int pre = s;
    for (int o = 1; o < 64; o <<= 1) {
        int t = __shfl_up(pre, o);
        if (lane >= o) pre += t;
    }
    if (lane == 63) wsum[w] = pre;
    __syncthreads();
    if (w == 0 && lane < 16) {
        int v = wsum[lane];
        for (int o = 1; o < 16; o <<= 1) {
            int t = __shfl_up(v, o, 16);
            if (lane >= o) v += t;
        }
        wsum[lane] = v;
    }
    __syncthreads();
    int waveoff = (w == 0) ? 0 : wsum[w - 1];
    int run = waveoff + pre - s;
#pragma unroll
    for (int j = 0; j < 10; ++j) {
        int i = base + j;
        if (i <= P_) offb[i] = run;
        run += c[j];
    }
}

// fill: store SRC NODE ID directly
__global__ void fill_src_kernel(const int* __restrict__ dst, const int* __restrict__ src,
                                const int* __restrict__ offb, int* __restrict__ cur,
                                int* __restrict__ csrc, int E_)
{
    int i = blockIdx.x * THREADS + threadIdx.x;
    if (i < E_) {
        int d = dst[i];
        int pos = atomicAdd(&cur[d], 1);
        csrc[offb[d] + pos] = src[i];
    }
}

// ------------------------------------------------------------------
// fused attention + gather + rms/sigmoid gate: 1 wave/particle, 4/block.
// lane = (g=lane>>4 edge-group, c=lane&15 col-chunk). KVb row: K 0..127,
// V 128..255. After cross-group reduce, all lanes hold the row sums ->
// gate computed in-register, AG = [gated | h] bf16 written directly.
// ------------------------------------------------------------------
__global__ __launch_bounds__(256) void edge_kernel(
    const int* __restrict__ offb, const int* __restrict__ csrc,
    const bf16_t* __restrict__ KVb, const bf16_t* __restrict__ Qb,
    const float* __restrict__ ph, const float* __restrict__ rms_w,
    const float* __restrict__ lin_w, bf16_t* __restrict__ AG, int P_)
{
    int tid = threadIdx.x;
    int p = blockIdx.x * 4 + (tid >> 6);
    if (p >= P_) return;
    int lane = tid & 63;
    int c = lane & 15, g = lane >> 4;

    bf16x8 q8 = *(const bf16x8*)(Qb + (size_t)p * 128 + c * 8);
    float qf[8];
#pragma unroll
    for (int j = 0; j < 8; ++j) qf[j] = (float)q8[j];

    int s0 = offb[p], e0 = offb[p + 1];
    float acc[8] = {};

    int i = s0 + g;
    for (; i + 12 < e0; i += 16) {
        int n0 = csrc[i], n1 = csrc[i + 4], n2 = csrc[i + 8], n3 = csrc[i + 12];
        const bf16_t* b0 = KVb + (size_t)n0 * 256 + c * 8;
        const bf16_t* b1 = KVb + (size_t)n1 * 256 + c * 8;
        const bf16_t* b2 = KVb + (size_t)n2 * 256 + c * 8;
        const bf16_t* b3 = KVb + (size_t)n3 * 256 + c * 8;
        bf16x8 k0 = *(const bf16x8*)b0, v0 = *(const bf16x8*)(b0 + 128);
        bf16x8 k1 = *(const bf16x8*)b1, v1 = *(const bf16x8*)(b1 + 128);
        bf16x8 k2 = *(const bf16x8*)b2, v2 = *(const bf16x8*)(b2 + 128);
        bf16x8 k3 = *(const bf16x8*)b3, v3 = *(const bf16x8*)(b3 + 128);
        float d0 = 0.f, d1 = 0.f, d2 = 0.f, d3 = 0.f;
#pragma unroll
        for (int j = 0; j < 8; ++j) {
            d0 += qf[j] * (float)k0[j]; d1 += qf[j] * (float)k1[j];
            d2 += qf[j] * (float)k2[j]; d3 += qf[j] * (float)k3[j];
        }
        d0 += __shfl_xor(d0, 1); d1 += __shfl_xor(d1, 1); d2 += __shfl_xor(d2, 1); d3 += __shfl_xor(d3, 1);
        d0 += __shfl_xor(d0, 2); d1 += __shfl_xor(d1, 2); d2 += __shfl_xor(d2, 2); d3 += __shfl_xor(d3, 2);
        d0 += __shfl_xor(d0, 4); d1 += __shfl_xor(d1, 4); d2 += __shfl_xor(d2, 4); d3 += __shfl_xor(d3, 4);
        d0 += __shfl_xor(d0, 8); d1 += __shfl_xor(d1, 8); d2 += __shfl_xor(d2, 8); d3 += __shfl_xor(d3, 8);
        float a0 = fmaxf(d0 * 0.1f, 0.f), a1 = fmaxf(d1 * 0.1f, 0.f);
        float a2 = fmaxf(d2 * 0.1f, 0.f), a3 = fmaxf(d3 * 0.1f, 0.f);
#pragma unroll
        for (int j = 0; j < 8; ++j)
            acc[j] += a0 * (float)v0[j] + a1 * (float)v1[j]
                    + a2 * (float)v2[j] + a3 * (float)v3[j];
    }
    for (; i < e0; i += 4) {
        int nA = csrc[i];
        const bf16_t* bA = KVb + (size_t)nA * 256 + c * 8;
        bf16x8 kA = *(const bf16x8*)bA;
        bf16x8 vA = *(const bf16x8*)(bA + 128);
        float dA = 0.f;
#pragma unroll
        for (int j = 0; j < 8; ++j) dA += qf[j] * (float)kA[j];
        dA += __shfl_xor(dA, 1);
        dA += __shfl_xor(dA, 2);
        dA += __shfl_xor(dA, 4);
        dA += __shfl_xor(dA, 8);
        float aA = fmaxf(dA * 0.1f, 0.f);
#pragma unroll
        for (int j = 0; j < 8; ++j) acc[j] += aA * (float)vA[j];
    }

    // reduce across the 4 edge-groups; afterwards every lane holds totals
#pragma unroll
    for (int j = 0; j < 8; ++j) {
        acc[j] += __shfl_xor(acc[j], 16);
        acc[j] += __shfl_xor(acc[j], 32);
    }

    // fused rms-norm * sigmoid gate (was gate_kernel)
    float ss = 0.f;
#pragma unroll
    for (int j = 0; j < 8; ++j) ss += acc[j] * acc[j];
    ss += __shfl_xor(ss, 1); ss += __shfl_xor(ss, 2); ss += __shfl_xor(ss, 4); ss += __shfl_xor(ss, 8);
    float scale = rsqrtf(ss * (1.f / 128.f) + 1e-6f);
    if (g == 0) {
        int cb = c * 8;
        const float* hp = ph + (size_t)p * 128 + cb;
        float4 ha = *(const float4*)hp, hb = *(const float4*)(hp + 4);
        float hv[8] = {ha.x, ha.y, ha.z, ha.w, hb.x, hb.y, hb.z, hb.w};
        bf16x8 gv, hvb;
#pragma unroll
        for (int j = 0; j < 8; ++j) {
            float wsv = acc[j];
            float rv = wsv * scale * rms_w[cb + j];
            gv[j] = (bf16_t)(rv * sigmoidf_(wsv * lin_w[cb + j]));
            hvb[j] = (bf16_t)hv[j];
        }
        *(bf16x8*)(AG + (size_t)p * 256 + cb) = gv;
        *(bf16x8*)(AG + (size_t)p * 256 + 128 + cb) = hvb;
    }
}

// ------------------------------------------------------------------
// gru+ln pointwise: read G768 [Mq,768] fp32 (gi|gh), h=ph fp32;
// compute h_new, LayerNorm -> LNb bf16 [Mq,128]
// ------------------------------------------------------------------
__global__ void gru_ln_kernel(const float* __restrict__ G768, const float* __restrict__ ph,
                              const float* __restrict__ ln_g, const float* __restrict__ ln_b,
                              bf16_t* __restrict__ LNb, int P_, int Mq)
{
    int tid = threadIdx.x;
    int g = tid >> 4, s = tid & 15;
    int p = blockIdx.x * 16 + g;
    if (p >= Mq) return;
    int cb = s * 8;
    if (p >= P_) {
        bf16x8 z = {};
        *(bf16x8*)(LNb + (size_t)p * 128 + cb) = z;
        return;
    }
    const float* G = G768 + (size_t)p * 768;
    float ir[8], iz[8], in_[8], hr[8], hz[8], hn_[8], hv[8];
#pragma unroll
    for (int q = 0; q < 2; ++q) {
        float4 v;
        v = *(const float4*)(G + cb + q * 4);        ir[q*4]=v.x; ir[q*4+1]=v.y; ir[q*4+2]=v.z; ir[q*4+3]=v.w;
        v = *(const float4*)(G + 128 + cb + q * 4);  iz[q*4]=v.x; iz[q*4+1]=v.y; iz[q*4+2]=v.z; iz[q*4+3]=v.w;
        v = *(const float4*)(G + 256 + cb + q * 4);  in_[q*4]=v.x; in_[q*4+1]=v.y; in_[q*4+2]=v.z; in_[q*4+3]=v.w;
        v = *(const float4*)(G + 384 + cb + q * 4);  hr[q*4]=v.x; hr[q*4+1]=v.y; hr[q*4+2]=v.z; hr[q*4+3]=v.w;
        v = *(const float4*)(G + 512 + cb + q * 4);  hz[q*4]=v.x; hz[q*4+1]=v.y; hz[q*4+2]=v.z; hz[q*4+3]=v.w;
        v = *(const float4*)(G + 640 + cb + q * 4);  hn_[q*4]=v.x; hn_[q*4+1]=v.y; hn_[q*4+2]=v.z; hn_[q*4+3]=v.w;
        v = *(const float4*)(ph + (size_t)p * 128 + cb + q * 4);
        hv[q*4]=v.x; hv[q*4+1]=v.y; hv[q*4+2]=v.z; hv[q*4+3]=v.w;
    }
    float hn[8];
    float sm = 0.f, sq = 0.f;
#pragma unroll
    for (int j = 0; j < 8; ++j) {
        float r = sigmoidf_(ir[j] + hr[j]);
        float z = sigmoidf_(iz[j] + hz[j]);
        float n = tanhf(in_[j] + r * hn_[j]);
        hn[j] = (1.f - z) * n + z * hv[j];
        sm += hn[j]; sq += hn[j] * hn[j];
    }
    sm += __shfl_xor(sm, 1); sm += __shfl_xor(sm, 2); sm += __shfl_xor(sm, 4); sm += __shfl_xor(sm, 8);
    sq += __shfl_xor(sq, 1); sq += __shfl_xor(sq, 2); sq += __shfl_xor(sq, 4); sq += __shfl_xor(sq, 8);
    float mu = sm * (1.f / 128.f);
    float var = sq * (1.f / 128.f) - mu * mu;
    float iv = rsqrtf(var + 1e-5f);
    bf16x8 o;
#pragma unroll
    for (int j = 0; j < 8; ++j) {
        int c = cb + j;
        o[j] = (bf16_t)((hn[j] - mu) * iv * ln_g[c] + ln_b[c]);
    }
    *(bf16x8*)(LNb + (size_t)p * 128 + cb) = o;
}

// ------------------------------------------------------------------
extern "C" void kernel_launch(void* const* d_in, const int* in_sizes, int n_in,
                              void* d_out, int out_size, void* d_ws, size_t ws_size,
                              hipStream_t stream)
{
    const float* nh      = (const float*)d_in[0];
    const float* energy  = (const float*)d_in[1];
    const float* eta     = (const float*)d_in[2];
    const float* phi     = (const float*)d_in[3];
    const float* layer   = (const float*)d_in[4];
    const float* eta_l   = (const float*)d_in[5];
    const float* phi_l   = (const float*)d_in[6];
    const float* ene_l   = (const float*)d_in[7];
    const float* track   = (const float*)d_in[8];
    const float* ph      = (const float*)d_in[9];
    const float* grep    = (const float*)d_in[10];
    const int*   esrc    = (const int*)d_in[11];
    const int*   edst    = (const int*)d_in[12];
    const float* W_key   = (const float*)d_in[13];
    const float* b_key   = (const float*)d_in[14];
    const float* W_val   = (const float*)d_in[15];
    const float* b_val   = (const float*)d_in[16];
    const float* W_q     = (const float*)d_in[17];
    const float* b_q     = (const float*)d_in[18];
    const float* W_ih    = (const float*)d_in[19];
    const float* b_ih    = (const float*)d_in[20];
    const float* W_hh    = (const float*)d_in[21];
    const float* b_hh    = (const float*)d_in[22];
    const float* ln_g    = (const float*)d_in[23];
    const float* ln_b    = (const float*)d_in[24];
    const float* W1      = (const float*)d_in[25];
    const float* b1      = (const float*)d_in[26];
    const float* W2      = (const float*)d_in[27];
    const float* b2      = (const float*)d_in[28];
    const float* rms_w   = (const float*)d_in[29];
    const float* lin_w   = (const float*)d_in[30];

    const int N = in_sizes[1];
    const int P = in_sizes[9] / 128;
    const int E = in_sizes[11];
    const int Mpad = ((N + 127) / 128) * 128;   // 100096
    const int Mq   = ((P + 127) / 128) * 128;   // 10112

    // workspace layout (byte offsets, 256B aligned)
    char* base = (char*)d_ws;
    size_t off = 0;
    auto alloc = [&](size_t bytes) { void* p = base + off; off = (off + bytes + 255) & ~(size_t)255; return p; };
    bf16_t* skipb = (bf16_t*)alloc((size_t)Mpad * 32 * 2);    // 6.4 MB
    bf16_t* WbfT  = (bf16_t*)alloc(256 * 288 * 2);
    bf16_t* Bpack = (bf16_t*)alloc(4 * 9 * 4 * 512 * 2);      // 144 KB fragment-order B
    bf16_t* WqT   = (bf16_t*)alloc(128 * 384 * 2);
    float*  bpn   = (float*)alloc(256 * 4);
    float*  bpq   = (float*)alloc(128 * 4);
    bf16_t* KVb   = (bf16_t*)alloc((size_t)Mpad * 256 * 2);   // 51.2 MB interleaved K|V
    bf16_t* Qb    = (bf16_t*)alloc((size_t)Mq * 128 * 2);
    // cnt and cur MUST be contiguous: prep2 zeroes cnt[0..2P)
    int*    cnt   = (int*)alloc((size_t)(2 * P) * 4);
    int*    cur   = cnt + P;
    int*    offb  = (int*)alloc((size_t)(P + 1) * 4);
    int*    csrc  = (int*)alloc((size_t)E * 4);
    // node-update buffers
    bf16_t* AG    = (bf16_t*)alloc((size_t)Mq * 256 * 2);
    bf16_t* BTg   = (bf16_t*)alloc(768 * 256 * 2);
    bf16_t* W1Tp  = (bf16_t*)alloc(128 * 128 * 2);
    bf16_t* W2Tp  = (bf16_t*)alloc(128 * 128 * 2);
    float*  bgru  = (float*)alloc(768 * 4);
    float*  b1p   = (float*)alloc(128 * 4);
    float*  G768  = (float*)alloc((size_t)Mq * 768 * 4);      // 31 MB
    bf16_t* LNb   = (bf16_t*)alloc((size_t)Mq * 128 * 2);
    bf16_t* M1    = (bf16_t*)alloc((size_t)Mq * 128 * 2);

    // 1. weight prep (+ cnt zero + AG pad zero) + skip features + B repack
    {
        int total = 256 * 288 + 128 * 384 + 256 + 128;
        prep_kernel<<<(total + THREADS - 1) / THREADS, THREADS, 0, stream>>>(
            W_key, W_val, W_q, b_key, b_val, b_q, WbfT, WqT, bpn, bpq);
        prep3_kernel<<<(4 * 9 * 4 * 512 + THREADS - 1) / THREADS, THREADS, 0, stream>>>(
            WbfT, Bpack);
        int padElems = (Mq - P) * 256;
        int total2 = 768 * 256 + 128 * 128 + 128 * 128 + 768 + 128 + 2 * P + padElems;
        prep2_kernel<<<(total2 + THREADS - 1) / THREADS, THREADS, 0, stream>>>(
            W_ih, W_hh, b_ih, b_hh, W1, b1, W2, BTg, W1Tp, W2Tp, bgru, b1p,
            cnt, 2 * P, AG, P, padElems);
        skip_kernel<<<(Mpad + THREADS - 1) / THREADS, THREADS, 0, stream>>>(
            energy, eta, phi, layer, eta_l, phi_l, ene_l, track, skipb, N, Mpad);
    }
    // 2. K/V GEMM: coalesced-stage + coalesced Bpack + barrier-free MFMA
    kv_gemm<<<Mpad / 64, THREADS, 0, stream>>>(nh, skipb, Bpack, bpn, KVb, N);
    mfma_gemm<1><<<dim3(1, Mq / 64), THREADS, 0, stream>>>(
        ph, grep, WqT, bpq, Qb, nullptr, 384, 0, P);
    // 3. CSR build (src ids stored directly)
    hist_kernel<<<(E + THREADS - 1) / THREADS, THREADS, 0, stream>>>(edst, cnt, E);
    scan_kernel<<<1, 1024, 0, stream>>>(cnt, offb, P);
    fill_src_kernel<<<(E + THREADS - 1) / THREADS, THREADS, 0, stream>>>(
        edst, esrc, offb, cur, csrc, E);
    // 4. fused attention + gather + gate -> AG
    edge_kernel<<<(P + 3) / 4, THREADS, 0, stream>>>(
        offb, csrc, KVb, Qb, ph, rms_w, lin_w, AG, P);
    // 5. node update: GRU GEMM -> pointwise+LN -> MLP1 -> MLP2+residual
    mfma_gemm<2><<<dim3(6, Mq / 64), THREADS, 0, stream>>>(
        AG, nullptr, BTg, bgru, G768, nullptr, 256, 0, Mq);
    gru_ln_kernel<<<Mq / 16, THREADS, 0, stream>>>(G768, ph, ln_g, ln_b, LNb, P, Mq);
    mfma_gemm<3><<<dim3(1, Mq / 64), THREADS, 0, stream>>>(
        LNb, nullptr, W1Tp, b1p, M1, nullptr, 128, 0, Mq);
    mfma_gemm<4><<<dim3(1, Mq / 64), THREADS, 0, stream>>>(
        M1, nullptr, W2Tp, b2, d_out, ph, 128, P, Mq);
}